// Round 4
// baseline (445.815 us; speedup 1.0000x reference)
//
#include <hip/hip_runtime.h>
#include <stdint.h>

#define TT 2048
#define DD 2048
#define NHH 16
#define HDD 128
#define BTT 4096   // B*T

typedef __attribute__((ext_vector_type(8))) short bf16x8;
typedef __attribute__((ext_vector_type(4))) float f32x4;

#define MF(a, b, c) __builtin_amdgcn_mfma_f32_16x16x32_bf16(a, b, c, 0, 0, 0)

__device__ __forceinline__ unsigned short f2bf(float f) {
    union { float f; uint32_t u; } v; v.f = f;
    uint32_t u = v.u;
    u += 0x7fffu + ((u >> 16) & 1u);   // RNE
    return (unsigned short)(u >> 16);
}

// async global->LDS, 16B per lane. LDS dest = wave-uniform base + lane*16B.
__device__ __forceinline__ void gld16(const unsigned short* g, unsigned short* l) {
    __builtin_amdgcn_global_load_lds(
        (const __attribute__((address_space(1))) unsigned int*)g,
        (__attribute__((address_space(3))) unsigned int*)l, 16, 0, 0);
}

// ---------------- weight fp32 -> bf16 cast ----------------
__global__ __launch_bounds__(256) void convert_w(const float* __restrict__ wq,
                                                 const float* __restrict__ wk,
                                                 const float* __restrict__ wv,
                                                 const float* __restrict__ wo,
                                                 unsigned short* __restrict__ out) {
    size_t gid = (size_t)blockIdx.x * 256 + threadIdx.x;
    size_t base = gid * 8;
    int which = (int)(base >> 22);
    const float* src = which == 0 ? wq : which == 1 ? wk : which == 2 ? wv : wo;
    size_t off = base & 4194303u;
    float4 a = ((const float4*)(src + off))[0];
    float4 b = ((const float4*)(src + off))[1];
    union { unsigned short us[8]; uint4 v; } pk;
    pk.us[0] = f2bf(a.x); pk.us[1] = f2bf(a.y); pk.us[2] = f2bf(a.z); pk.us[3] = f2bf(a.w);
    pk.us[4] = f2bf(b.x); pk.us[5] = f2bf(b.y); pk.us[6] = f2bf(b.z); pk.us[7] = f2bf(b.w);
    *(uint4*)(out + base) = pk.v;
}

// ---------------- RMSNorm fp32 -> bf16 ----------------
__global__ __launch_bounds__(256) void rmsnorm_k(const float* __restrict__ x,
                                                 const float* __restrict__ w,
                                                 unsigned short* __restrict__ xn) {
    const int row = blockIdx.x;
    const int tid = threadIdx.x;
    const float* xr = x + (size_t)row * DD;
    float4 a = ((const float4*)xr)[tid * 2];
    float4 b = ((const float4*)xr)[tid * 2 + 1];
    float ss = a.x*a.x + a.y*a.y + a.z*a.z + a.w*a.w
             + b.x*b.x + b.y*b.y + b.z*b.z + b.w*b.w;
    #pragma unroll
    for (int m = 1; m < 64; m <<= 1) ss += __shfl_xor(ss, m, 64);
    __shared__ float wss[4];
    if ((tid & 63) == 0) wss[tid >> 6] = ss;
    __syncthreads();
    float total = wss[0] + wss[1] + wss[2] + wss[3];
    float norm = sqrtf(total) * 0.022097086912079612f;
    float inv = 1.0f / (norm + 1e-8f);
    float4 wa = ((const float4*)w)[tid * 2];
    float4 wb = ((const float4*)w)[tid * 2 + 1];
    union { unsigned short us[8]; uint4 v; } pk;
    pk.us[0] = f2bf(wa.x * a.x * inv); pk.us[1] = f2bf(wa.y * a.y * inv);
    pk.us[2] = f2bf(wa.z * a.z * inv); pk.us[3] = f2bf(wa.w * a.w * inv);
    pk.us[4] = f2bf(wb.x * b.x * inv); pk.us[5] = f2bf(wb.y * b.y * inv);
    pk.us[6] = f2bf(wb.z * b.z * inv); pk.us[7] = f2bf(wb.w * b.w * inv);
    ((uint4*)(xn + (size_t)row * DD))[tid] = pk.v;
}

// ---------------- 256x256 8-phase GEMM core (T2+T3+T4+T5, m201-style) ----------------
// 512 thr = 8 waves (2M x 4N). BK=64. LDS 128 KiB: 2 bufs x (A 16384 + B 16384 elems).
// Swizzle (rule #21, both-sides): LDS chunk (row, c8) holds global chunk (row, c8^(row&7));
// stage source per-lane chunk = (l&7)^(l>>3); ds_read applies ^(row&7) -> 2-way conflicts (free).
// Raw s_barrier per phase (NOT __syncthreads: that drains vmcnt). Stages for tile kt+1 stay
// in flight across all intra-tile barriers; single vmcnt(0) drain at tile boundary, after
// ~600cy of MFMA has covered the L2 latency.
__device__ __forceinline__ void gemm256_core(const unsigned short* __restrict__ Ag,
                                             const unsigned short* __restrict__ Bg,
                                             unsigned short* lds, f32x4 acc[8][4]) {
    const int tid = threadIdx.x;
    const int wave = tid >> 6, lane = tid & 63;
    const int wm = wave >> 2, wn = wave & 3;
    const int l15 = lane & 15, lq = lane >> 4, r7 = l15 & 7;
    const int gr = lane >> 3;
    const size_t goff = (size_t)gr * DD + (size_t)((((lane & 7) ^ gr)) * 8);
    const int xk0 = (lq ^ r7) * 8;         // kc=0 chunk (swizzled)
    const int xk1 = ((4 + lq) ^ r7) * 8;   // kc=1 chunk
    const int aro = (wm * 128 + l15) * 64;
    const int bro = 16384 + (wn * 64 + l15) * 64;
    const int sw16 = wave * 16;

    // ---- prologue: stage tile 0 into buf 0 (8 gld16/wave) ----
    #pragma unroll
    for (int c = 0; c < 2; c++) {
        gld16(Ag + (size_t)(sw16 + c * 8) * DD + goff,       lds + (sw16 + c * 8) * 64);
        gld16(Ag + (size_t)(128 + sw16 + c * 8) * DD + goff, lds + (128 + sw16 + c * 8) * 64);
        gld16(Bg + (size_t)(sw16 + c * 8) * DD + goff,       lds + 16384 + (sw16 + c * 8) * 64);
        gld16(Bg + (size_t)(128 + sw16 + c * 8) * DD + goff, lds + 16384 + (128 + sw16 + c * 8) * 64);
    }
    asm volatile("s_waitcnt vmcnt(0)" ::: "memory");
    __builtin_amdgcn_sched_barrier(0);
    __builtin_amdgcn_s_barrier();

    for (int kt = 0; kt < DD / 64; kt++) {
        const int cur = (kt & 1) << 15;    // *32768 elems
        const int nxt = cur ^ 32768;
        const bool hn = (kt + 1 < DD / 64);
        const int kn = (kt + 1) * 64;
        const unsigned short* ac = lds + cur + aro;
        const unsigned short* bc = lds + cur + bro;
        bf16x8 af[4][2], bA[2][2], bB[2][2];

        // ---- phase 0: read a[m0..3], b[n0..1]; stage A-half0(next); MFMA q00 ----
        #pragma unroll
        for (int m = 0; m < 4; m++) {
            af[m][0] = *(const bf16x8*)(ac + m * 1024 + xk0);
            af[m][1] = *(const bf16x8*)(ac + m * 1024 + xk1);
        }
        #pragma unroll
        for (int n = 0; n < 2; n++) {
            bA[n][0] = *(const bf16x8*)(bc + n * 1024 + xk0);
            bA[n][1] = *(const bf16x8*)(bc + n * 1024 + xk1);
        }
        if (hn) {
            gld16(Ag + (size_t)(sw16 + 0) * DD + kn + goff, lds + nxt + (sw16 + 0) * 64);
            gld16(Ag + (size_t)(sw16 + 8) * DD + kn + goff, lds + nxt + (sw16 + 8) * 64);
        }
        __builtin_amdgcn_s_barrier();
        asm volatile("s_waitcnt lgkmcnt(0)" ::: "memory");
        __builtin_amdgcn_sched_barrier(0);
        __builtin_amdgcn_s_setprio(1);
        #pragma unroll
        for (int m = 0; m < 4; m++)
            #pragma unroll
            for (int n = 0; n < 2; n++) {
                acc[m][n] = MF(af[m][0], bA[n][0], acc[m][n]);
                acc[m][n] = MF(af[m][1], bA[n][1], acc[m][n]);
            }
        __builtin_amdgcn_s_setprio(0);
        __builtin_amdgcn_s_barrier();

        // ---- phase 1: read b[n2..3]; stage A-half1(next); MFMA q01 ----
        #pragma unroll
        for (int n = 0; n < 2; n++) {
            bB[n][0] = *(const bf16x8*)(bc + (2 + n) * 1024 + xk0);
            bB[n][1] = *(const bf16x8*)(bc + (2 + n) * 1024 + xk1);
        }
        if (hn) {
            gld16(Ag + (size_t)(128 + sw16 + 0) * DD + kn + goff, lds + nxt + (128 + sw16 + 0) * 64);
            gld16(Ag + (size_t)(128 + sw16 + 8) * DD + kn + goff, lds + nxt + (128 + sw16 + 8) * 64);
        }
        __builtin_amdgcn_s_barrier();
        asm volatile("s_waitcnt lgkmcnt(0)" ::: "memory");
        __builtin_amdgcn_sched_barrier(0);
        __builtin_amdgcn_s_setprio(1);
        #pragma unroll
        for (int m = 0; m < 4; m++)
            #pragma unroll
            for (int n = 0; n < 2; n++) {
                acc[m][2 + n] = MF(af[m][0], bB[n][0], acc[m][2 + n]);
                acc[m][2 + n] = MF(af[m][1], bB[n][1], acc[m][2 + n]);
            }
        __builtin_amdgcn_s_setprio(0);
        __builtin_amdgcn_s_barrier();

        // ---- phase 2: read a[m4..7]; stage B-half0(next); MFMA q10 ----
        #pragma unroll
        for (int m = 0; m < 4; m++) {
            af[m][0] = *(const bf16x8*)(ac + (4 + m) * 1024 + xk0);
            af[m][1] = *(const bf16x8*)(ac + (4 + m) * 1024 + xk1);
        }
        if (hn) {
            gld16(Bg + (size_t)(sw16 + 0) * DD + kn + goff, lds + nxt + 16384 + (sw16 + 0) * 64);
            gld16(Bg + (size_t)(sw16 + 8) * DD + kn + goff, lds + nxt + 16384 + (sw16 + 8) * 64);
        }
        __builtin_amdgcn_s_barrier();
        asm volatile("s_waitcnt lgkmcnt(0)" ::: "memory");
        __builtin_amdgcn_sched_barrier(0);
        __builtin_amdgcn_s_setprio(1);
        #pragma unroll
        for (int m = 0; m < 4; m++)
            #pragma unroll
            for (int n = 0; n < 2; n++) {
                acc[4 + m][n] = MF(af[m][0], bA[n][0], acc[4 + m][n]);
                acc[4 + m][n] = MF(af[m][1], bA[n][1], acc[4 + m][n]);
            }
        __builtin_amdgcn_s_setprio(0);
        __builtin_amdgcn_s_barrier();

        // ---- phase 3: stage B-half1(next); MFMA q11; tile-boundary drain ----
        if (hn) {
            gld16(Bg + (size_t)(128 + sw16 + 0) * DD + kn + goff, lds + nxt + 16384 + (128 + sw16 + 0) * 64);
            gld16(Bg + (size_t)(128 + sw16 + 8) * DD + kn + goff, lds + nxt + 16384 + (128 + sw16 + 8) * 64);
        }
        __builtin_amdgcn_s_barrier();
        __builtin_amdgcn_s_setprio(1);
        #pragma unroll
        for (int m = 0; m < 4; m++)
            #pragma unroll
            for (int n = 0; n < 2; n++) {
                acc[4 + m][2 + n] = MF(af[m][0], bB[n][0], acc[4 + m][2 + n]);
                acc[4 + m][2 + n] = MF(af[m][1], bB[n][1], acc[4 + m][2 + n]);
            }
        __builtin_amdgcn_s_setprio(0);
        asm volatile("s_waitcnt vmcnt(0)" ::: "memory");   // next tile's stages complete
        __builtin_amdgcn_sched_barrier(0);
        __builtin_amdgcn_s_barrier();                       // cross-wave visibility
    }
}

// fused QKV: 384 blocks x 512 thr; flattened+XCD-swizzled grid; which = byy>>3
__global__ __launch_bounds__(512, 2) void gemm_qkv(const unsigned short* __restrict__ A,
                                                   const unsigned short* __restrict__ W3,
                                                   unsigned short* __restrict__ O3) {
    __shared__ __align__(16) unsigned short lds[65536];   // 128 KiB
    const int nwg = 384;
    const int orig = blockIdx.y * 16 + blockIdx.x;
    const int id = (orig & 7) * (nwg / 8) + (orig >> 3);  // bijective XCD swizzle (nwg%8==0)
    const int bx = id & 15, byy = id >> 4;
    const int which = byy >> 3;
    const unsigned short* Bw = W3 + (size_t)which * DD * DD;
    unsigned short* C = O3 + (size_t)which * BTT * DD;
    const int m0 = bx * 256, n0 = (byy & 7) * 256;
    const f32x4 zf = {0.f, 0.f, 0.f, 0.f};
    f32x4 acc[8][4];
    #pragma unroll
    for (int m = 0; m < 8; m++)
        #pragma unroll
        for (int n = 0; n < 4; n++) acc[m][n] = zf;
    gemm256_core(A + (size_t)m0 * DD, Bw + (size_t)n0 * DD, lds, acc);
    const int wave = threadIdx.x >> 6, lane = threadIdx.x & 63;
    const int wm = wave >> 2, wn = wave & 3;
    const int l15 = lane & 15, lq = lane >> 4;
    #pragma unroll
    for (int m = 0; m < 8; m++) {
        const int row = m0 + wm * 128 + m * 16 + lq * 4;
        #pragma unroll
        for (int n = 0; n < 4; n++) {
            const int col = n0 + wn * 64 + n * 16 + l15;
            #pragma unroll
            for (int r = 0; r < 4; r++)
                C[(size_t)(row + r) * DD + col] = f2bf(acc[m][n][r]);
        }
    }
}

// final proj, fp32 out: 128 blocks x 512 thr
__global__ __launch_bounds__(512, 2) void gemm_out(const unsigned short* __restrict__ A,
                                                   const unsigned short* __restrict__ Bw,
                                                   float* __restrict__ C) {
    __shared__ __align__(16) unsigned short lds[65536];   // 128 KiB
    const int nwg = 128;
    const int orig = blockIdx.y * 16 + blockIdx.x;
    const int id = (orig & 7) * (nwg / 8) + (orig >> 3);
    const int bx = id & 15, byy = id >> 4;
    const int m0 = bx * 256, n0 = byy * 256;
    const f32x4 zf = {0.f, 0.f, 0.f, 0.f};
    f32x4 acc[8][4];
    #pragma unroll
    for (int m = 0; m < 8; m++)
        #pragma unroll
        for (int n = 0; n < 4; n++) acc[m][n] = zf;
    gemm256_core(A + (size_t)m0 * DD, Bw + (size_t)n0 * DD, lds, acc);
    const int wave = threadIdx.x >> 6, lane = threadIdx.x & 63;
    const int wm = wave >> 2, wn = wave & 3;
    const int l15 = lane & 15, lq = lane >> 4;
    #pragma unroll
    for (int m = 0; m < 8; m++) {
        const int row = m0 + wm * 128 + m * 16 + lq * 4;
        #pragma unroll
        for (int n = 0; n < 4; n++) {
            const int col = n0 + wn * 64 + n * 16 + l15;
            #pragma unroll
            for (int r = 0; r < 4; r++)
                C[(size_t)(row + r) * DD + col] = acc[m][n][r];
        }
    }
}

// ---------------- fused causal flash attention, paired q-tiles (R3, unchanged) ----------------
__global__ __launch_bounds__(256) void attn_fused(const unsigned short* __restrict__ q,
                                                  const unsigned short* __restrict__ k,
                                                  const unsigned short* __restrict__ v,
                                                  unsigned short* __restrict__ o) {
    constexpr int LKK = 136;  // 128 + 8 pad
    constexpr int LPP = 72;   // 64 + 8 pad
    __shared__ __align__(16) unsigned short Ks[2][64 * LKK];
    __shared__ __align__(16) unsigned short Vts[128 * 64];
    __shared__ __align__(16) unsigned short Ps[4 * 16 * LPP];
    const int h = blockIdx.y, b = blockIdx.z;
    const int tid = threadIdx.x, wave = tid >> 6, lane = tid & 63;
    const int l15 = lane & 15, lq = lane >> 4;
    const size_t rowbase = (size_t)b * TT;
    const int hcol = h * HDD;
    const float scale = 0.08838834764831845f;  // HD^-0.5
    unsigned short* Pw = Ps + wave * 16 * LPP;
    const f32x4 zf = {0.f, 0.f, 0.f, 0.f};

    uint4 kr0, kr1, kr2, kr3, vr0, vr1, vr2, vr3;
    const int sidx = tid * 8;
    const int srr = sidx >> 7;
    const int sc  = sidx & 127;
    const int swz = ((sc >> 3) & 7) << 3;
    const int srs0 = (srr +  0) ^ swz;
    const int srs1 = (srr + 16) ^ swz;
    const int srs2 = (srr + 32) ^ swz;
    const int srs3 = (srr + 48) ^ swz;

    for (int half = 0; half < 2; half++) {
        const int qj = (half == 0) ? blockIdx.x : 31 - blockIdx.x;
        const int qt0 = qj * 64;
        bf16x8 aq[4];
        {
            const unsigned short* qrp = q + (rowbase + qt0 + wave * 16 + l15) * DD + hcol;
            #pragma unroll
            for (int kk = 0; kk < 4; kk++)
                aq[kk] = *(const bf16x8*)(qrp + kk * 32 + lq * 8);
        }
        f32x4 acc_o[8];
        #pragma unroll
        for (int jh = 0; jh < 8; jh++) acc_o[jh] = zf;
        float m_i[4], l_i[4];
        #pragma unroll
        for (int r = 0; r < 4; r++) { m_i[r] = -1e30f; l_i[r] = 0.f; }
        const int qp0 = qt0 + wave * 16 + lq * 4;
        const int nkt = qj + 1;

        __syncthreads();
        {
            const unsigned short* kg = k + rowbase * DD + hcol;
            const unsigned short* vg = v + rowbase * DD + hcol;
            kr0 = *(const uint4*)(kg + (size_t)(srr +  0) * DD + sc);
            kr1 = *(const uint4*)(kg + (size_t)(srr + 16) * DD + sc);
            kr2 = *(const uint4*)(kg + (size_t)(srr + 32) * DD + sc);
            kr3 = *(const uint4*)(kg + (size_t)(srr + 48) * DD + sc);
            vr0 = *(const uint4*)(vg + (size_t)(srr +  0) * DD + sc);
            vr1 = *(const uint4*)(vg + (size_t)(srr + 16) * DD + sc);
            vr2 = *(const uint4*)(vg + (size_t)(srr + 32) * DD + sc);
            vr3 = *(const uint4*)(vg + (size_t)(srr + 48) * DD + sc);
            unsigned short* ksb = &Ks[0][0];
            *(uint4*)(ksb + (srr +  0) * LKK + sc) = kr0;
            *(uint4*)(ksb + (srr + 16) * LKK + sc) = kr1;
            *(uint4*)(ksb + (srr + 32) * LKK + sc) = kr2;
            *(uint4*)(ksb + (srr + 48) * LKK + sc) = kr3;
            if (nkt > 1) {
                const unsigned short* kg1 = k + (rowbase + 64) * DD + hcol;
                kr0 = *(const uint4*)(kg1 + (size_t)(srr +  0) * DD + sc);
                kr1 = *(const uint4*)(kg1 + (size_t)(srr + 16) * DD + sc);
                kr2 = *(const uint4*)(kg1 + (size_t)(srr + 32) * DD + sc);
                kr3 = *(const uint4*)(kg1 + (size_t)(srr + 48) * DD + sc);
            }
        }

        for (int kt = 0; kt < nkt; kt++) {
            const int cur = kt & 1;
            __syncthreads();
            {
                const unsigned short* d0 = (const unsigned short*)&vr0;
                const unsigned short* d1 = (const unsigned short*)&vr1;
                const unsigned short* d2 = (const unsigned short*)&vr2;
                const unsigned short* d3 = (const unsigned short*)&vr3;
                #pragma unroll
                for (int jj = 0; jj < 8; jj++) {
                    Vts[(sc + jj) * 64 + srs0] = d0[jj];
                    Vts[(sc + jj) * 64 + srs1] = d1[jj];
                    Vts[(sc + jj) * 64 + srs2] = d2[jj];
                    Vts[(sc + jj) * 64 + srs3] = d3[jj];
                }
            }
            if (kt + 1 < nkt) {
                unsigned short* ksb = &Ks[cur ^ 1][0];
                *(uint4*)(ksb + (srr +  0) * LKK + sc) = kr0;
                *(uint4*)(ksb + (srr + 16) * LKK + sc) = kr1;
                *(uint4*)(ksb + (srr + 32) * LKK + sc) = kr2;
                *(uint4*)(ksb + (srr + 48) * LKK + sc) = kr3;
            }
            if (kt + 2 < nkt) {
                const unsigned short* kg = k + (rowbase + (kt + 2) * 64) * DD + hcol;
                kr0 = *(const uint4*)(kg + (size_t)(srr +  0) * DD + sc);
                kr1 = *(const uint4*)(kg + (size_t)(srr + 16) * DD + sc);
                kr2 = *(const uint4*)(kg + (size_t)(srr + 32) * DD + sc);
                kr3 = *(const uint4*)(kg + (size_t)(srr + 48) * DD + sc);
            }
            if (kt + 1 < nkt) {
                const unsigned short* vg = v + (rowbase + (kt + 1) * 64) * DD + hcol;
                vr0 = *(const uint4*)(vg + (size_t)(srr +  0) * DD + sc);
                vr1 = *(const uint4*)(vg + (size_t)(srr + 16) * DD + sc);
                vr2 = *(const uint4*)(vg + (size_t)(srr + 32) * DD + sc);
                vr3 = *(const uint4*)(vg + (size_t)(srr + 48) * DD + sc);
            }
            const unsigned short* ksc = &Ks[cur][0];
            f32x4 accs[4];
            #pragma unroll
            for (int j = 0; j < 4; j++) accs[j] = zf;
            __builtin_amdgcn_s_setprio(1);
            #pragma unroll
            for (int j = 0; j < 4; j++)
                #pragma unroll
                for (int kk = 0; kk < 4; kk++) {
                    bf16x8 bk = *(const bf16x8*)(&ksc[(j * 16 + l15) * LKK + kk * 32 + lq * 8]);
                    accs[j] = MF(aq[kk], bk, accs[j]);
                }
            __builtin_amdgcn_s_setprio(0);
            const int kbase = kt * 64;
            float rowmax[4] = {-1e30f, -1e30f, -1e30f, -1e30f};
            #pragma unroll
            for (int j = 0; j < 4; j++) {
                const int kp = kbase + j * 16 + l15;
                #pragma unroll
                for (int r = 0; r < 4; r++) {
                    float s = accs[j][r] * scale;
                    s = (kp > qp0 + r) ? -1e30f : s;
                    accs[j][r] = s;
                    rowmax[r] = fmaxf(rowmax[r], s);
                }
            }
            #pragma unroll
            for (int r = 0; r < 4; r++) {
                float mx = rowmax[r];
                mx = fmaxf(mx, __shfl_xor(mx, 1, 64));
                mx = fmaxf(mx, __shfl_xor(mx, 2, 64));
                mx = fmaxf(mx, __shfl_xor(mx, 4, 64));
                mx = fmaxf(mx, __shfl_xor(mx, 8, 64));
                float m_new = fmaxf(m_i[r], mx);
                float al = __expf(m_i[r] - m_new);
                m_i[r] = m_new;
                l_i[r] *= al;
                #pragma unroll
                for (int jh = 0; jh < 8; jh++) acc_o[jh][r] *= al;
            }
            float rowsum[4] = {0.f, 0.f, 0.f, 0.f};
            #pragma unroll
            for (int j = 0; j < 4; j++)
                #pragma unroll
                for (int r = 0; r < 4; r++) {
                    float p = __expf(accs[j][r] - m_i[r]);
                    rowsum[r] += p;
                    Pw[(lq * 4 + r) * LPP + j * 16 + l15] = f2bf(p);
                }
            #pragma unroll
            for (int r = 0; r < 4; r++) {
                float s = rowsum[r];
                s += __shfl_xor(s, 1, 64);
                s += __shfl_xor(s, 2, 64);
                s += __shfl_xor(s, 4, 64);
                s += __shfl_xor(s, 8, 64);
                l_i[r] += s;
            }
            __syncthreads();
            bf16x8 ap[2];
            #pragma unroll
            for (int kk = 0; kk < 2; kk++)
                ap[kk] = *(const bf16x8*)(&Pw[l15 * LPP + kk * 32 + lq * 8]);
            __builtin_amdgcn_s_setprio(1);
            #pragma unroll
            for (int jh = 0; jh < 8; jh++) {
                const int hd = jh * 16 + l15;
                const int vswz = ((hd >> 3) & 7) << 3;
                #pragma unroll
                for (int kk = 0; kk < 2; kk++) {
                    bf16x8 bv = *(const bf16x8*)(&Vts[hd * 64 + ((kk * 32 + lq * 8) ^ vswz)]);
                    acc_o[jh] = MF(ap[kk], bv, acc_o[jh]);
                }
            }
            __builtin_amdgcn_s_setprio(0);
        }
        #pragma unroll
        for (int jh = 0; jh < 8; jh++) {
            const int col = hcol + jh * 16 + l15;
            #pragma unroll
            for (int r = 0; r < 4; r++)
                o[(rowbase + qp0 + r) * DD + col] = f2bf(acc_o[jh][r] * (1.0f / l_i[r]));
        }
    }
}

extern "C" void kernel_launch(void* const* d_in, const int* in_sizes, int n_in,
                              void* d_out, int out_size, void* d_ws, size_t ws_size,
                              hipStream_t stream) {
    const float* x      = (const float*)d_in[0];
    // d_in[1] = attn_mask: deterministic causal tril -> handled analytically
    const float* w_norm = (const float*)d_in[2];
    const float* wq     = (const float*)d_in[3];
    const float* wk     = (const float*)d_in[4];
    const float* wv     = (const float*)d_in[5];
    const float* wo     = (const float*)d_in[6];

    unsigned short* wbf = (unsigned short*)d_ws;                 // [4][D*D]
    unsigned short* xn  = wbf + (size_t)4 * DD * DD;             // [BT][D]
    unsigned short* qb  = xn + (size_t)BTT * DD;
    unsigned short* kb  = qb + (size_t)BTT * DD;
    unsigned short* vb  = kb + (size_t)BTT * DD;
    unsigned short* ab  = vb + (size_t)BTT * DD;

    convert_w<<<8192, 256, 0, stream>>>(wq, wk, wv, wo, wbf);
    rmsnorm_k<<<BTT, 256, 0, stream>>>(x, w_norm, xn);
    dim3 gqkv(16, 24);
    gemm_qkv<<<gqkv, 512, 0, stream>>>(xn, wbf, qb);
    dim3 gattn(16, NHH, 2);
    attn_fused<<<gattn, 256, 0, stream>>>(qb, kb, vb, ab);
    dim3 gout(16, 8);
    gemm_out<<<gout, 512, 0, stream>>>(ab, wbf + (size_t)3 * DD * DD, (float*)d_out);
}

// Round 5
// 429.723 us; speedup vs baseline: 1.0374x; 1.0374x over previous
//
#include <hip/hip_runtime.h>
#include <stdint.h>

#define TT 2048
#define DD 2048
#define NHH 16
#define HDD 128
#define BTT 4096   // B*T

typedef __attribute__((ext_vector_type(8))) short bf16x8;
typedef __attribute__((ext_vector_type(4))) float f32x4;

#define MF(a, b, c) __builtin_amdgcn_mfma_f32_16x16x32_bf16(a, b, c, 0, 0, 0)

__device__ __forceinline__ unsigned short f2bf(float f) {
    union { float f; uint32_t u; } v; v.f = f;
    uint32_t u = v.u;
    u += 0x7fffu + ((u >> 16) & 1u);   // RNE
    return (unsigned short)(u >> 16);
}

// async global->LDS, 16B per lane. LDS dest = wave-uniform base + lane*16B.
__device__ __forceinline__ void gld16(const unsigned short* g, unsigned short* l) {
    __builtin_amdgcn_global_load_lds(
        (const __attribute__((address_space(1))) unsigned int*)g,
        (__attribute__((address_space(3))) unsigned int*)l, 16, 0, 0);
}

// ---------------- weight fp32 -> bf16 cast ----------------
__global__ __launch_bounds__(256) void convert_w(const float* __restrict__ wq,
                                                 const float* __restrict__ wk,
                                                 const float* __restrict__ wv,
                                                 const float* __restrict__ wo,
                                                 unsigned short* __restrict__ out) {
    size_t gid = (size_t)blockIdx.x * 256 + threadIdx.x;
    size_t base = gid * 8;
    int which = (int)(base >> 22);
    const float* src = which == 0 ? wq : which == 1 ? wk : which == 2 ? wv : wo;
    size_t off = base & 4194303u;
    float4 a = ((const float4*)(src + off))[0];
    float4 b = ((const float4*)(src + off))[1];
    union { unsigned short us[8]; uint4 v; } pk;
    pk.us[0] = f2bf(a.x); pk.us[1] = f2bf(a.y); pk.us[2] = f2bf(a.z); pk.us[3] = f2bf(a.w);
    pk.us[4] = f2bf(b.x); pk.us[5] = f2bf(b.y); pk.us[6] = f2bf(b.z); pk.us[7] = f2bf(b.w);
    *(uint4*)(out + base) = pk.v;
}

// ---------------- RMSNorm fp32 -> bf16 ----------------
__global__ __launch_bounds__(256) void rmsnorm_k(const float* __restrict__ x,
                                                 const float* __restrict__ w,
                                                 unsigned short* __restrict__ xn) {
    const int row = blockIdx.x;
    const int tid = threadIdx.x;
    const float* xr = x + (size_t)row * DD;
    float4 a = ((const float4*)xr)[tid * 2];
    float4 b = ((const float4*)xr)[tid * 2 + 1];
    float ss = a.x*a.x + a.y*a.y + a.z*a.z + a.w*a.w
             + b.x*b.x + b.y*b.y + b.z*b.z + b.w*b.w;
    #pragma unroll
    for (int m = 1; m < 64; m <<= 1) ss += __shfl_xor(ss, m, 64);
    __shared__ float wss[4];
    if ((tid & 63) == 0) wss[tid >> 6] = ss;
    __syncthreads();
    float total = wss[0] + wss[1] + wss[2] + wss[3];
    float norm = sqrtf(total) * 0.022097086912079612f;
    float inv = 1.0f / (norm + 1e-8f);
    float4 wa = ((const float4*)w)[tid * 2];
    float4 wb = ((const float4*)w)[tid * 2 + 1];
    union { unsigned short us[8]; uint4 v; } pk;
    pk.us[0] = f2bf(wa.x * a.x * inv); pk.us[1] = f2bf(wa.y * a.y * inv);
    pk.us[2] = f2bf(wa.z * a.z * inv); pk.us[3] = f2bf(wa.w * a.w * inv);
    pk.us[4] = f2bf(wb.x * b.x * inv); pk.us[5] = f2bf(wb.y * b.y * inv);
    pk.us[6] = f2bf(wb.z * b.z * inv); pk.us[7] = f2bf(wb.w * b.w * inv);
    ((uint4*)(xn + (size_t)row * DD))[tid] = pk.v;
}

// ---------------- 128x256 early-issue/late-drain GEMM core ----------------
// 512 thr = 8 waves (2M x 4N), per-wave 64x64 out, BK=64.
// LDS 96 KiB: 2 bufs x (A 128x64 + B 256x64). XOR chunk swizzle (verified R4).
// R5: ALL 6 staging gld16 for tile kt+1 issued in phase A; SINGLE vmcnt(0) at tile
// boundary -> last load has a full K-tile (~1200cy) of MFMA/ds_read cover (>= HBM 900cy).
// This removes the m218 "drain0" failure mode of R4. Raw s_barrier (no vmcnt drain).
__device__ __forceinline__ void gemm128x256_core(const unsigned short* __restrict__ Ag,
                                                 const unsigned short* __restrict__ Bg,
                                                 unsigned short* lds, f32x4 acc[4][4]) {
    const int tid = threadIdx.x;
    const int wave = tid >> 6, lane = tid & 63;
    const int wm = wave >> 2, wn = wave & 3;
    const int l15 = lane & 15, lq = lane >> 4, r7 = l15 & 7;
    const int gr = lane >> 3;
    const size_t goff = (size_t)gr * DD + (size_t)(((lane & 7) ^ gr) * 8);
    const int xk0 = (lq ^ r7) * 8;         // k-half 0 chunk (de-swizzled)
    const int xk1 = ((4 + lq) ^ r7) * 8;   // k-half 1 chunk
    const int aro = (wm * 64 + l15) * 64;
    const int bro = 8192 + (wn * 64 + l15) * 64;
    const int swA = wave * 16;   // wave's A staging row base (2 chunks of 8 rows)
    const int swB = wave * 32;   // wave's B staging row base (4 chunks of 8 rows)

    // ---- prologue: stage tile 0 into buf 0 ----
    #pragma unroll
    for (int c = 0; c < 2; c++)
        gld16(Ag + (size_t)(swA + c * 8) * DD + goff, lds + (swA + c * 8) * 64);
    #pragma unroll
    for (int c = 0; c < 4; c++)
        gld16(Bg + (size_t)(swB + c * 8) * DD + goff, lds + 8192 + (swB + c * 8) * 64);
    asm volatile("s_waitcnt vmcnt(0)" ::: "memory");
    __builtin_amdgcn_sched_barrier(0);
    __builtin_amdgcn_s_barrier();

    for (int kt = 0; kt < DD / 64; kt++) {
        const int cur = (kt & 1) ? 24576 : 0;
        const int nxt = 24576 - cur;
        const bool hn = (kt + 1 < DD / 64);
        const int kn = (kt + 1) * 64;
        const unsigned short* ac = lds + cur + aro;
        const unsigned short* bc = lds + cur + bro;
        bf16x8 afA[2][2], afB[2][2], bA[2][2], bB[2][2];

        // ---- phase A: read all A-frags + B n0/n1; issue ALL next-tile stages; MFMA n0/n1 ----
        #pragma unroll
        for (int m = 0; m < 2; m++) {
            afA[m][0] = *(const bf16x8*)(ac + m * 1024 + xk0);
            afA[m][1] = *(const bf16x8*)(ac + m * 1024 + xk1);
            afB[m][0] = *(const bf16x8*)(ac + (2 + m) * 1024 + xk0);
            afB[m][1] = *(const bf16x8*)(ac + (2 + m) * 1024 + xk1);
        }
        #pragma unroll
        for (int n = 0; n < 2; n++) {
            bA[n][0] = *(const bf16x8*)(bc + n * 1024 + xk0);
            bA[n][1] = *(const bf16x8*)(bc + n * 1024 + xk1);
        }
        if (hn) {
            #pragma unroll
            for (int c = 0; c < 2; c++)
                gld16(Ag + (size_t)(swA + c * 8) * DD + kn + goff,
                      lds + nxt + (swA + c * 8) * 64);
            #pragma unroll
            for (int c = 0; c < 4; c++)
                gld16(Bg + (size_t)(swB + c * 8) * DD + kn + goff,
                      lds + nxt + 8192 + (swB + c * 8) * 64);
        }
        __builtin_amdgcn_s_barrier();
        asm volatile("s_waitcnt lgkmcnt(0)" ::: "memory");
        __builtin_amdgcn_sched_barrier(0);
        __builtin_amdgcn_s_setprio(1);
        #pragma unroll
        for (int m = 0; m < 2; m++)
            #pragma unroll
            for (int n = 0; n < 2; n++) {
                acc[m][n]     = MF(afA[m][0], bA[n][0], acc[m][n]);
                acc[m][n]     = MF(afA[m][1], bA[n][1], acc[m][n]);
                acc[2 + m][n] = MF(afB[m][0], bA[n][0], acc[2 + m][n]);
                acc[2 + m][n] = MF(afB[m][1], bA[n][1], acc[2 + m][n]);
            }
        __builtin_amdgcn_s_setprio(0);
        __builtin_amdgcn_s_barrier();

        // ---- phase B: read B n2/n3; MFMA n2/n3; boundary drain ----
        #pragma unroll
        for (int n = 0; n < 2; n++) {
            bB[n][0] = *(const bf16x8*)(bc + (2 + n) * 1024 + xk0);
            bB[n][1] = *(const bf16x8*)(bc + (2 + n) * 1024 + xk1);
        }
        __builtin_amdgcn_s_barrier();
        asm volatile("s_waitcnt lgkmcnt(0)" ::: "memory");
        __builtin_amdgcn_sched_barrier(0);
        __builtin_amdgcn_s_setprio(1);
        #pragma unroll
        for (int m = 0; m < 2; m++)
            #pragma unroll
            for (int n = 0; n < 2; n++) {
                acc[m][2 + n]     = MF(afA[m][0], bB[n][0], acc[m][2 + n]);
                acc[m][2 + n]     = MF(afA[m][1], bB[n][1], acc[m][2 + n]);
                acc[2 + m][2 + n] = MF(afB[m][0], bB[n][0], acc[2 + m][2 + n]);
                acc[2 + m][2 + n] = MF(afB[m][1], bB[n][1], acc[2 + m][2 + n]);
            }
        __builtin_amdgcn_s_setprio(0);
        asm volatile("s_waitcnt vmcnt(0)" ::: "memory");   // next tile's stages landed
        __builtin_amdgcn_sched_barrier(0);
        __builtin_amdgcn_s_barrier();                       // cross-wave visibility
    }
}

// fused QKV: 768 blocks (32x8x3) x 512 thr = 3 exact full GPU rounds
__global__ __launch_bounds__(512, 2) void gemm_qkv(const unsigned short* __restrict__ A,
                                                   const unsigned short* __restrict__ W3,
                                                   unsigned short* __restrict__ O3) {
    __shared__ __align__(16) unsigned short lds[49152];   // 96 KiB
    const int orig = blockIdx.y * 32 + blockIdx.x;        // grid (32, 24)
    const int id = (orig & 7) * 96 + (orig >> 3);         // bijective XCD swizzle (768%8==0)
    const int which = id >> 8;
    const int rem = id & 255;
    const int bn = rem >> 5, bm = rem & 31;               // consecutive ids share B panel
    const unsigned short* Bw = W3 + (size_t)which * DD * DD;
    unsigned short* C = O3 + (size_t)which * BTT * DD;
    const int m0 = bm * 128, n0 = bn * 256;
    const f32x4 zf = {0.f, 0.f, 0.f, 0.f};
    f32x4 acc[4][4];
    #pragma unroll
    for (int m = 0; m < 4; m++)
        #pragma unroll
        for (int n = 0; n < 4; n++) acc[m][n] = zf;
    gemm128x256_core(A + (size_t)m0 * DD, Bw + (size_t)n0 * DD, lds, acc);
    const int wave = threadIdx.x >> 6, lane = threadIdx.x & 63;
    const int wm = wave >> 2, wn = wave & 3;
    const int l15 = lane & 15, lq = lane >> 4;
    #pragma unroll
    for (int m = 0; m < 4; m++) {
        const int row = m0 + wm * 64 + m * 16 + lq * 4;
        #pragma unroll
        for (int n = 0; n < 4; n++) {
            const int col = n0 + wn * 64 + n * 16 + l15;
            #pragma unroll
            for (int r = 0; r < 4; r++)
                C[(size_t)(row + r) * DD + col] = f2bf(acc[m][n][r]);
        }
    }
}

// final proj, fp32 out: 256 blocks (32x8) x 512 thr = 1 exact full GPU round
__global__ __launch_bounds__(512, 2) void gemm_out(const unsigned short* __restrict__ A,
                                                   const unsigned short* __restrict__ Bw,
                                                   float* __restrict__ C) {
    __shared__ __align__(16) unsigned short lds[49152];   // 96 KiB
    const int orig = blockIdx.y * 32 + blockIdx.x;        // grid (32, 8)
    const int id = (orig & 7) * 32 + (orig >> 3);         // bijective XCD swizzle (256%8==0)
    const int bn = id >> 5, bm = id & 31;
    const int m0 = bm * 128, n0 = bn * 256;
    const f32x4 zf = {0.f, 0.f, 0.f, 0.f};
    f32x4 acc[4][4];
    #pragma unroll
    for (int m = 0; m < 4; m++)
        #pragma unroll
        for (int n = 0; n < 4; n++) acc[m][n] = zf;
    gemm128x256_core(A + (size_t)m0 * DD, Bw + (size_t)n0 * DD, lds, acc);
    const int wave = threadIdx.x >> 6, lane = threadIdx.x & 63;
    const int wm = wave >> 2, wn = wave & 3;
    const int l15 = lane & 15, lq = lane >> 4;
    #pragma unroll
    for (int m = 0; m < 4; m++) {
        const int row = m0 + wm * 64 + m * 16 + lq * 4;
        #pragma unroll
        for (int n = 0; n < 4; n++) {
            const int col = n0 + wn * 64 + n * 16 + l15;
            #pragma unroll
            for (int r = 0; r < 4; r++)
                C[(size_t)(row + r) * DD + col] = acc[m][n][r];
        }
    }
}

// ---------------- fused causal flash attention, paired q-tiles (R3, unchanged) ----------------
__global__ __launch_bounds__(256) void attn_fused(const unsigned short* __restrict__ q,
                                                  const unsigned short* __restrict__ k,
                                                  const unsigned short* __restrict__ v,
                                                  unsigned short* __restrict__ o) {
    constexpr int LKK = 136;  // 128 + 8 pad
    constexpr int LPP = 72;   // 64 + 8 pad
    __shared__ __align__(16) unsigned short Ks[2][64 * LKK];
    __shared__ __align__(16) unsigned short Vts[128 * 64];
    __shared__ __align__(16) unsigned short Ps[4 * 16 * LPP];
    const int h = blockIdx.y, b = blockIdx.z;
    const int tid = threadIdx.x, wave = tid >> 6, lane = tid & 63;
    const int l15 = lane & 15, lq = lane >> 4;
    const size_t rowbase = (size_t)b * TT;
    const int hcol = h * HDD;
    const float scale = 0.08838834764831845f;  // HD^-0.5
    unsigned short* Pw = Ps + wave * 16 * LPP;
    const f32x4 zf = {0.f, 0.f, 0.f, 0.f};

    uint4 kr0, kr1, kr2, kr3, vr0, vr1, vr2, vr3;
    const int sidx = tid * 8;
    const int srr = sidx >> 7;
    const int sc  = sidx & 127;
    const int swz = ((sc >> 3) & 7) << 3;
    const int srs0 = (srr +  0) ^ swz;
    const int srs1 = (srr + 16) ^ swz;
    const int srs2 = (srr + 32) ^ swz;
    const int srs3 = (srr + 48) ^ swz;

    for (int half = 0; half < 2; half++) {
        const int qj = (half == 0) ? blockIdx.x : 31 - blockIdx.x;
        const int qt0 = qj * 64;
        bf16x8 aq[4];
        {
            const unsigned short* qrp = q + (rowbase + qt0 + wave * 16 + l15) * DD + hcol;
            #pragma unroll
            for (int kk = 0; kk < 4; kk++)
                aq[kk] = *(const bf16x8*)(qrp + kk * 32 + lq * 8);
        }
        f32x4 acc_o[8];
        #pragma unroll
        for (int jh = 0; jh < 8; jh++) acc_o[jh] = zf;
        float m_i[4], l_i[4];
        #pragma unroll
        for (int r = 0; r < 4; r++) { m_i[r] = -1e30f; l_i[r] = 0.f; }
        const int qp0 = qt0 + wave * 16 + lq * 4;
        const int nkt = qj + 1;

        __syncthreads();
        {
            const unsigned short* kg = k + rowbase * DD + hcol;
            const unsigned short* vg = v + rowbase * DD + hcol;
            kr0 = *(const uint4*)(kg + (size_t)(srr +  0) * DD + sc);
            kr1 = *(const uint4*)(kg + (size_t)(srr + 16) * DD + sc);
            kr2 = *(const uint4*)(kg + (size_t)(srr + 32) * DD + sc);
            kr3 = *(const uint4*)(kg + (size_t)(srr + 48) * DD + sc);
            vr0 = *(const uint4*)(vg + (size_t)(srr +  0) * DD + sc);
            vr1 = *(const uint4*)(vg + (size_t)(srr + 16) * DD + sc);
            vr2 = *(const uint4*)(vg + (size_t)(srr + 32) * DD + sc);
            vr3 = *(const uint4*)(vg + (size_t)(srr + 48) * DD + sc);
            unsigned short* ksb = &Ks[0][0];
            *(uint4*)(ksb + (srr +  0) * LKK + sc) = kr0;
            *(uint4*)(ksb + (srr + 16) * LKK + sc) = kr1;
            *(uint4*)(ksb + (srr + 32) * LKK + sc) = kr2;
            *(uint4*)(ksb + (srr + 48) * LKK + sc) = kr3;
            if (nkt > 1) {
                const unsigned short* kg1 = k + (rowbase + 64) * DD + hcol;
                kr0 = *(const uint4*)(kg1 + (size_t)(srr +  0) * DD + sc);
                kr1 = *(const uint4*)(kg1 + (size_t)(srr + 16) * DD + sc);
                kr2 = *(const uint4*)(kg1 + (size_t)(srr + 32) * DD + sc);
                kr3 = *(const uint4*)(kg1 + (size_t)(srr + 48) * DD + sc);
            }
        }

        for (int kt = 0; kt < nkt; kt++) {
            const int cur = kt & 1;
            __syncthreads();
            {
                const unsigned short* d0 = (const unsigned short*)&vr0;
                const unsigned short* d1 = (const unsigned short*)&vr1;
                const unsigned short* d2 = (const unsigned short*)&vr2;
                const unsigned short* d3 = (const unsigned short*)&vr3;
                #pragma unroll
                for (int jj = 0; jj < 8; jj++) {
                    Vts[(sc + jj) * 64 + srs0] = d0[jj];
                    Vts[(sc + jj) * 64 + srs1] = d1[jj];
                    Vts[(sc + jj) * 64 + srs2] = d2[jj];
                    Vts[(sc + jj) * 64 + srs3] = d3[jj];
                }
            }
            if (kt + 1 < nkt) {
                unsigned short* ksb = &Ks[cur ^ 1][0];
                *(uint4*)(ksb + (srr +  0) * LKK + sc) = kr0;
                *(uint4*)(ksb + (srr + 16) * LKK + sc) = kr1;
                *(uint4*)(ksb + (srr + 32) * LKK + sc) = kr2;
                *(uint4*)(ksb + (srr + 48) * LKK + sc) = kr3;
            }
            if (kt + 2 < nkt) {
                const unsigned short* kg = k + (rowbase + (kt + 2) * 64) * DD + hcol;
                kr0 = *(const uint4*)(kg + (size_t)(srr +  0) * DD + sc);
                kr1 = *(const uint4*)(kg + (size_t)(srr + 16) * DD + sc);
                kr2 = *(const uint4*)(kg + (size_t)(srr + 32) * DD + sc);
                kr3 = *(const uint4*)(kg + (size_t)(srr + 48) * DD + sc);
            }
            if (kt + 1 < nkt) {
                const unsigned short* vg = v + (rowbase + (kt + 1) * 64) * DD + hcol;
                vr0 = *(const uint4*)(vg + (size_t)(srr +  0) * DD + sc);
                vr1 = *(const uint4*)(vg + (size_t)(srr + 16) * DD + sc);
                vr2 = *(const uint4*)(vg + (size_t)(srr + 32) * DD + sc);
                vr3 = *(const uint4*)(vg + (size_t)(srr + 48) * DD + sc);
            }
            const unsigned short* ksc = &Ks[cur][0];
            f32x4 accs[4];
            #pragma unroll
            for (int j = 0; j < 4; j++) accs[j] = zf;
            __builtin_amdgcn_s_setprio(1);
            #pragma unroll
            for (int j = 0; j < 4; j++)
                #pragma unroll
                for (int kk = 0; kk < 4; kk++) {
                    bf16x8 bk = *(const bf16x8*)(&ksc[(j * 16 + l15) * LKK + kk * 32 + lq * 8]);
                    accs[j] = MF(aq[kk], bk, accs[j]);
                }
            __builtin_amdgcn_s_setprio(0);
            const int kbase = kt * 64;
            float rowmax[4] = {-1e30f, -1e30f, -1e30f, -1e30f};
            #pragma unroll
            for (int j = 0; j < 4; j++) {
                const int kp = kbase + j * 16 + l15;
                #pragma unroll
                for (int r = 0; r < 4; r++) {
                    float s = accs[j][r] * scale;
                    s = (kp > qp0 + r) ? -1e30f : s;
                    accs[j][r] = s;
                    rowmax[r] = fmaxf(rowmax[r], s);
                }
            }
            #pragma unroll
            for (int r = 0; r < 4; r++) {
                float mx = rowmax[r];
                mx = fmaxf(mx, __shfl_xor(mx, 1, 64));
                mx = fmaxf(mx, __shfl_xor(mx, 2, 64));
                mx = fmaxf(mx, __shfl_xor(mx, 4, 64));
                mx = fmaxf(mx, __shfl_xor(mx, 8, 64));
                float m_new = fmaxf(m_i[r], mx);
                float al = __expf(m_i[r] - m_new);
                m_i[r] = m_new;
                l_i[r] *= al;
                #pragma unroll
                for (int jh = 0; jh < 8; jh++) acc_o[jh][r] *= al;
            }
            float rowsum[4] = {0.f, 0.f, 0.f, 0.f};
            #pragma unroll
            for (int j = 0; j < 4; j++)
                #pragma unroll
                for (int r = 0; r < 4; r++) {
                    float p = __expf(accs[j][r] - m_i[r]);
                    rowsum[r] += p;
                    Pw[(lq * 4 + r) * LPP + j * 16 + l15] = f2bf(p);
                }
            #pragma unroll
            for (int r = 0; r < 4; r++) {
                float s = rowsum[r];
                s += __shfl_xor(s, 1, 64);
                s += __shfl_xor(s, 2, 64);
                s += __shfl_xor(s, 4, 64);
                s += __shfl_xor(s, 8, 64);
                l_i[r] += s;
            }
            __syncthreads();
            bf16x8 ap[2];
            #pragma unroll
            for (int kk = 0; kk < 2; kk++)
                ap[kk] = *(const bf16x8*)(&Pw[l15 * LPP + kk * 32 + lq * 8]);
            __builtin_amdgcn_s_setprio(1);
            #pragma unroll
            for (int jh = 0; jh < 8; jh++) {
                const int hd = jh * 16 + l15;
                const int vswz = ((hd >> 3) & 7) << 3;
                #pragma unroll
                for (int kk = 0; kk < 2; kk++) {
                    bf16x8 bv = *(const bf16x8*)(&Vts[hd * 64 + ((kk * 32 + lq * 8) ^ vswz)]);
                    acc_o[jh] = MF(ap[kk], bv, acc_o[jh]);
                }
            }
            __builtin_amdgcn_s_setprio(0);
        }
        #pragma unroll
        for (int jh = 0; jh < 8; jh++) {
            const int col = hcol + jh * 16 + l15;
            #pragma unroll
            for (int r = 0; r < 4; r++)
                o[(rowbase + qp0 + r) * DD + col] = f2bf(acc_o[jh][r] * (1.0f / l_i[r]));
        }
    }
}

extern "C" void kernel_launch(void* const* d_in, const int* in_sizes, int n_in,
                              void* d_out, int out_size, void* d_ws, size_t ws_size,
                              hipStream_t stream) {
    const float* x      = (const float*)d_in[0];
    // d_in[1] = attn_mask: deterministic causal tril -> handled analytically
    const float* w_norm = (const float*)d_in[2];
    const float* wq     = (const float*)d_in[3];
    const float* wk     = (const float*)d_in[4];
    const float* wv     = (const float*)d_in[5];
    const float* wo     = (const float*)d_in[6];

    unsigned short* wbf = (unsigned short*)d_ws;                 // [4][D*D]
    unsigned short* xn  = wbf + (size_t)4 * DD * DD;             // [BT][D]
    unsigned short* qb  = xn + (size_t)BTT * DD;
    unsigned short* kb  = qb + (size_t)BTT * DD;
    unsigned short* vb  = kb + (size_t)BTT * DD;
    unsigned short* ab  = vb + (size_t)BTT * DD;

    convert_w<<<8192, 256, 0, stream>>>(wq, wk, wv, wo, wbf);
    rmsnorm_k<<<BTT, 256, 0, stream>>>(x, w_norm, xn);
    dim3 gqkv(32, 24);
    gemm_qkv<<<gqkv, 512, 0, stream>>>(xn, wbf, qb);
    dim3 gattn(16, NHH, 2);
    attn_fused<<<gattn, 256, 0, stream>>>(qb, kb, vb, ab);
    dim3 gout(32, 8);
    gemm_out<<<gout, 512, 0, stream>>>(ab, wbf + (size_t)3 * DD * DD, (float*)d_out);
}

// Round 6
// 426.784 us; speedup vs baseline: 1.0446x; 1.0069x over previous
//
#include <hip/hip_runtime.h>
#include <stdint.h>

#define TT 2048
#define DD 2048
#define NHH 16
#define HDD 128
#define BTT 4096   // B*T

typedef __attribute__((ext_vector_type(8))) short bf16x8;
typedef __attribute__((ext_vector_type(4))) float f32x4;

#define MF(a, b, c) __builtin_amdgcn_mfma_f32_16x16x32_bf16(a, b, c, 0, 0, 0)

__device__ __forceinline__ unsigned short f2bf(float f) {
    union { float f; uint32_t u; } v; v.f = f;
    uint32_t u = v.u;
    u += 0x7fffu + ((u >> 16) & 1u);   // RNE
    return (unsigned short)(u >> 16);
}

// async global->LDS, 16B per lane. LDS dest = wave-uniform base + lane*16B.
__device__ __forceinline__ void gld16(const unsigned short* g, unsigned short* l) {
    __builtin_amdgcn_global_load_lds(
        (const __attribute__((address_space(1))) unsigned int*)g,
        (__attribute__((address_space(3))) unsigned int*)l, 16, 0, 0);
}

// ---------------- weight fp32 -> bf16 cast ----------------
__global__ __launch_bounds__(256) void convert_w(const float* __restrict__ wq,
                                                 const float* __restrict__ wk,
                                                 const float* __restrict__ wv,
                                                 const float* __restrict__ wo,
                                                 unsigned short* __restrict__ out) {
    size_t gid = (size_t)blockIdx.x * 256 + threadIdx.x;
    size_t base = gid * 8;
    int which = (int)(base >> 22);
    const float* src = which == 0 ? wq : which == 1 ? wk : which == 2 ? wv : wo;
    size_t off = base & 4194303u;
    float4 a = ((const float4*)(src + off))[0];
    float4 b = ((const float4*)(src + off))[1];
    union { unsigned short us[8]; uint4 v; } pk;
    pk.us[0] = f2bf(a.x); pk.us[1] = f2bf(a.y); pk.us[2] = f2bf(a.z); pk.us[3] = f2bf(a.w);
    pk.us[4] = f2bf(b.x); pk.us[5] = f2bf(b.y); pk.us[6] = f2bf(b.z); pk.us[7] = f2bf(b.w);
    *(uint4*)(out + base) = pk.v;
}

// ---------------- RMSNorm fp32 -> bf16 ----------------
__global__ __launch_bounds__(256) void rmsnorm_k(const float* __restrict__ x,
                                                 const float* __restrict__ w,
                                                 unsigned short* __restrict__ xn) {
    const int row = blockIdx.x;
    const int tid = threadIdx.x;
    const float* xr = x + (size_t)row * DD;
    float4 a = ((const float4*)xr)[tid * 2];
    float4 b = ((const float4*)xr)[tid * 2 + 1];
    float ss = a.x*a.x + a.y*a.y + a.z*a.z + a.w*a.w
             + b.x*b.x + b.y*b.y + b.z*b.z + b.w*b.w;
    #pragma unroll
    for (int m = 1; m < 64; m <<= 1) ss += __shfl_xor(ss, m, 64);
    __shared__ float wss[4];
    if ((tid & 63) == 0) wss[tid >> 6] = ss;
    __syncthreads();
    float total = wss[0] + wss[1] + wss[2] + wss[3];
    float norm = sqrtf(total) * 0.022097086912079612f;
    float inv = 1.0f / (norm + 1e-8f);
    float4 wa = ((const float4*)w)[tid * 2];
    float4 wb = ((const float4*)w)[tid * 2 + 1];
    union { unsigned short us[8]; uint4 v; } pk;
    pk.us[0] = f2bf(wa.x * a.x * inv); pk.us[1] = f2bf(wa.y * a.y * inv);
    pk.us[2] = f2bf(wa.z * a.z * inv); pk.us[3] = f2bf(wa.w * a.w * inv);
    pk.us[4] = f2bf(wb.x * b.x * inv); pk.us[5] = f2bf(wb.y * b.y * inv);
    pk.us[6] = f2bf(wb.z * b.z * inv); pk.us[7] = f2bf(wb.w * b.w * inv);
    ((uint4*)(xn + (size_t)row * DD))[tid] = pk.v;
}

// ---------------- 128x256 early-issue/late-drain GEMM core (R5, unchanged) ----------------
__device__ __forceinline__ void gemm128x256_core(const unsigned short* __restrict__ Ag,
                                                 const unsigned short* __restrict__ Bg,
                                                 unsigned short* lds, f32x4 acc[4][4]) {
    const int tid = threadIdx.x;
    const int wave = tid >> 6, lane = tid & 63;
    const int wm = wave >> 2, wn = wave & 3;
    const int l15 = lane & 15, lq = lane >> 4, r7 = l15 & 7;
    const int gr = lane >> 3;
    const size_t goff = (size_t)gr * DD + (size_t)(((lane & 7) ^ gr) * 8);
    const int xk0 = (lq ^ r7) * 8;         // k-half 0 chunk (de-swizzled)
    const int xk1 = ((4 + lq) ^ r7) * 8;   // k-half 1 chunk
    const int aro = (wm * 64 + l15) * 64;
    const int bro = 8192 + (wn * 64 + l15) * 64;
    const int swA = wave * 16;   // wave's A staging row base (2 chunks of 8 rows)
    const int swB = wave * 32;   // wave's B staging row base (4 chunks of 8 rows)

    // ---- prologue: stage tile 0 into buf 0 ----
    #pragma unroll
    for (int c = 0; c < 2; c++)
        gld16(Ag + (size_t)(swA + c * 8) * DD + goff, lds + (swA + c * 8) * 64);
    #pragma unroll
    for (int c = 0; c < 4; c++)
        gld16(Bg + (size_t)(swB + c * 8) * DD + goff, lds + 8192 + (swB + c * 8) * 64);
    asm volatile("s_waitcnt vmcnt(0)" ::: "memory");
    __builtin_amdgcn_sched_barrier(0);
    __builtin_amdgcn_s_barrier();

    for (int kt = 0; kt < DD / 64; kt++) {
        const int cur = (kt & 1) ? 24576 : 0;
        const int nxt = 24576 - cur;
        const bool hn = (kt + 1 < DD / 64);
        const int kn = (kt + 1) * 64;
        const unsigned short* ac = lds + cur + aro;
        const unsigned short* bc = lds + cur + bro;
        bf16x8 afA[2][2], afB[2][2], bA[2][2], bB[2][2];

        // ---- phase A: read all A-frags + B n0/n1; issue ALL next-tile stages; MFMA n0/n1 ----
        #pragma unroll
        for (int m = 0; m < 2; m++) {
            afA[m][0] = *(const bf16x8*)(ac + m * 1024 + xk0);
            afA[m][1] = *(const bf16x8*)(ac + m * 1024 + xk1);
            afB[m][0] = *(const bf16x8*)(ac + (2 + m) * 1024 + xk0);
            afB[m][1] = *(const bf16x8*)(ac + (2 + m) * 1024 + xk1);
        }
        #pragma unroll
        for (int n = 0; n < 2; n++) {
            bA[n][0] = *(const bf16x8*)(bc + n * 1024 + xk0);
            bA[n][1] = *(const bf16x8*)(bc + n * 1024 + xk1);
        }
        if (hn) {
            #pragma unroll
            for (int c = 0; c < 2; c++)
                gld16(Ag + (size_t)(swA + c * 8) * DD + kn + goff,
                      lds + nxt + (swA + c * 8) * 64);
            #pragma unroll
            for (int c = 0; c < 4; c++)
                gld16(Bg + (size_t)(swB + c * 8) * DD + kn + goff,
                      lds + nxt + 8192 + (swB + c * 8) * 64);
        }
        __builtin_amdgcn_s_barrier();
        asm volatile("s_waitcnt lgkmcnt(0)" ::: "memory");
        __builtin_amdgcn_sched_barrier(0);
        __builtin_amdgcn_s_setprio(1);
        #pragma unroll
        for (int m = 0; m < 2; m++)
            #pragma unroll
            for (int n = 0; n < 2; n++) {
                acc[m][n]     = MF(afA[m][0], bA[n][0], acc[m][n]);
                acc[m][n]     = MF(afA[m][1], bA[n][1], acc[m][n]);
                acc[2 + m][n] = MF(afB[m][0], bA[n][0], acc[2 + m][n]);
                acc[2 + m][n] = MF(afB[m][1], bA[n][1], acc[2 + m][n]);
            }
        __builtin_amdgcn_s_setprio(0);
        __builtin_amdgcn_s_barrier();

        // ---- phase B: read B n2/n3; MFMA n2/n3; boundary drain ----
        #pragma unroll
        for (int n = 0; n < 2; n++) {
            bB[n][0] = *(const bf16x8*)(bc + (2 + n) * 1024 + xk0);
            bB[n][1] = *(const bf16x8*)(bc + (2 + n) * 1024 + xk1);
        }
        __builtin_amdgcn_s_barrier();
        asm volatile("s_waitcnt lgkmcnt(0)" ::: "memory");
        __builtin_amdgcn_sched_barrier(0);
        __builtin_amdgcn_s_setprio(1);
        #pragma unroll
        for (int m = 0; m < 2; m++)
            #pragma unroll
            for (int n = 0; n < 2; n++) {
                acc[m][2 + n]     = MF(afA[m][0], bB[n][0], acc[m][2 + n]);
                acc[m][2 + n]     = MF(afA[m][1], bB[n][1], acc[m][2 + n]);
                acc[2 + m][2 + n] = MF(afB[m][0], bB[n][0], acc[2 + m][2 + n]);
                acc[2 + m][2 + n] = MF(afB[m][1], bB[n][1], acc[2 + m][2 + n]);
            }
        __builtin_amdgcn_s_setprio(0);
        asm volatile("s_waitcnt vmcnt(0)" ::: "memory");   // next tile's stages landed
        __builtin_amdgcn_sched_barrier(0);
        __builtin_amdgcn_s_barrier();                       // cross-wave visibility
    }
}

// fused QKV: 768 blocks (32x8x3) x 512 thr
__global__ __launch_bounds__(512, 2) void gemm_qkv(const unsigned short* __restrict__ A,
                                                   const unsigned short* __restrict__ W3,
                                                   unsigned short* __restrict__ O3) {
    __shared__ __align__(16) unsigned short lds[49152];   // 96 KiB
    const int orig = blockIdx.y * 32 + blockIdx.x;        // grid (32, 24)
    const int id = (orig & 7) * 96 + (orig >> 3);         // bijective XCD swizzle (768%8==0)
    const int which = id >> 8;
    const int rem = id & 255;
    const int bn = rem >> 5, bm = rem & 31;               // consecutive ids share B panel
    const unsigned short* Bw = W3 + (size_t)which * DD * DD;
    unsigned short* C = O3 + (size_t)which * BTT * DD;
    const int m0 = bm * 128, n0 = bn * 256;
    const f32x4 zf = {0.f, 0.f, 0.f, 0.f};
    f32x4 acc[4][4];
    #pragma unroll
    for (int m = 0; m < 4; m++)
        #pragma unroll
        for (int n = 0; n < 4; n++) acc[m][n] = zf;
    gemm128x256_core(A + (size_t)m0 * DD, Bw + (size_t)n0 * DD, lds, acc);
    const int wave = threadIdx.x >> 6, lane = threadIdx.x & 63;
    const int wm = wave >> 2, wn = wave & 3;
    const int l15 = lane & 15, lq = lane >> 4;
    #pragma unroll
    for (int m = 0; m < 4; m++) {
        const int row = m0 + wm * 64 + m * 16 + lq * 4;
        #pragma unroll
        for (int n = 0; n < 4; n++) {
            const int col = n0 + wn * 64 + n * 16 + l15;
            #pragma unroll
            for (int r = 0; r < 4; r++)
                C[(size_t)(row + r) * DD + col] = f2bf(acc[m][n][r]);
        }
    }
}

// final proj, fp32 out: 256 blocks (32x8) x 512 thr
__global__ __launch_bounds__(512, 2) void gemm_out(const unsigned short* __restrict__ A,
                                                   const unsigned short* __restrict__ Bw,
                                                   float* __restrict__ C) {
    __shared__ __align__(16) unsigned short lds[49152];   // 96 KiB
    const int orig = blockIdx.y * 32 + blockIdx.x;        // grid (32, 8)
    const int id = (orig & 7) * 32 + (orig >> 3);         // bijective XCD swizzle (256%8==0)
    const int bn = id >> 5, bm = id & 31;
    const int m0 = bm * 128, n0 = bn * 256;
    const f32x4 zf = {0.f, 0.f, 0.f, 0.f};
    f32x4 acc[4][4];
    #pragma unroll
    for (int m = 0; m < 4; m++)
        #pragma unroll
        for (int n = 0; n < 4; n++) acc[m][n] = zf;
    gemm128x256_core(A + (size_t)m0 * DD, Bw + (size_t)n0 * DD, lds, acc);
    const int wave = threadIdx.x >> 6, lane = threadIdx.x & 63;
    const int wm = wave >> 2, wn = wave & 3;
    const int l15 = lane & 15, lq = lane >> 4;
    #pragma unroll
    for (int m = 0; m < 4; m++) {
        const int row = m0 + wm * 64 + m * 16 + lq * 4;
        #pragma unroll
        for (int n = 0; n < 4; n++) {
            const int col = n0 + wn * 64 + n * 16 + l15;
            #pragma unroll
            for (int r = 0; r < 4; r++)
                C[(size_t)(row + r) * DD + col] = acc[m][n][r];
        }
    }
}

// ---------------- fused causal flash attention, paired q-tiles ----------------
// R6: LDS-op reduction on the R3 skeleton (attn is LDS-issue-bound: 10.7% MfmaUtil,
// 2.2e7 bank-conflict cycles).
//  (1) K staging -> global_load_lds with pre-swizzled global source (rule #21):
//      Ks unpadded [64][128]; LDS[row][c] = K[row][c ^ (row&7)] (8-elem chunks);
//      QK^T read applies the inverse XOR. Kills 4 b128 ds_writes + 4 uint4 loads
//      + 16 VGPR per thread.
//  (2) V commit -> kpos-pair packed ds_write_b32: thread stages rows {2pr, 2pr+1},
//      writes lo|hi<<16 -> 16 b32 writes @2-way (free) vs 32 u16 @4-way.
//      Element mapping identical to R3 (XOR hits bits 3-5, pair bit is bit 0):
//      PV read path unchanged.
__global__ __launch_bounds__(256) void attn_fused(const unsigned short* __restrict__ q,
                                                  const unsigned short* __restrict__ k,
                                                  const unsigned short* __restrict__ v,
                                                  unsigned short* __restrict__ o) {
    constexpr int LPP = 72;   // 64 + 8 pad
    __shared__ __align__(16) unsigned short Ks[2][64 * 128];
    __shared__ __align__(16) unsigned short Vts[128 * 64];
    __shared__ __align__(16) unsigned short Ps[4 * 16 * LPP];
    const int h = blockIdx.y, b = blockIdx.z;
    const int tid = threadIdx.x, wave = tid >> 6, lane = tid & 63;
    const int l15 = lane & 15, lq = lane >> 4;
    const size_t rowbase = (size_t)b * TT;
    const int hcol = h * HDD;
    const float scale = 0.08838834764831845f;  // HD^-0.5
    unsigned short* Pw = Ps + wave * 16 * LPP;
    const f32x4 zf = {0.f, 0.f, 0.f, 0.f};

    // V staging mapping: thread handles kpos pair {2pr, 2pr+1}, cols [hc, hc+16)
    uint4 vr0, vr1, vr2, vr3;
    const int pr = tid >> 3;            // 0..31
    const int hc = (tid & 7) * 16;      // 0,16,...,112
    const int vsw0 = (2 * pr) ^ (((hc >> 3) & 7) << 3);        // swizzled row, cols hc..hc+7
    const int vsw1 = (2 * pr) ^ ((((hc + 8) >> 3) & 7) << 3);  // cols hc+8..hc+15

    // K gld16 source: per issue-group base r0, row = r0 + (lane>>4), chunk = (lane&15)^(row&7)
    const int klrow = lane >> 4;        // 0..3
    const int klch  = lane & 15;

    for (int half = 0; half < 2; half++) {
        const int qj = (half == 0) ? blockIdx.x : 31 - blockIdx.x;
        const int qt0 = qj * 64;
        bf16x8 aq[4];
        {
            const unsigned short* qrp = q + (rowbase + qt0 + wave * 16 + l15) * DD + hcol;
            #pragma unroll
            for (int kk = 0; kk < 4; kk++)
                aq[kk] = *(const bf16x8*)(qrp + kk * 32 + lq * 8);
        }
        f32x4 acc_o[8];
        #pragma unroll
        for (int jh = 0; jh < 8; jh++) acc_o[jh] = zf;
        float m_i[4], l_i[4];
        #pragma unroll
        for (int r = 0; r < 4; r++) { m_i[r] = -1e30f; l_i[r] = 0.f; }
        const int qp0 = qt0 + wave * 16 + lq * 4;
        const int nkt = qj + 1;

        // ---- prologue: protect prior half's LDS; stage K0 via gld16; load V0 regs ----
        __syncthreads();
        {
            const unsigned short* kg = k + rowbase * DD + hcol;
            const unsigned short* vg = v + rowbase * DD + hcol;
            #pragma unroll
            for (int i = 0; i < 4; i++) {
                const int r0 = wave * 16 + i * 4;
                const int row = r0 + klrow;
                const int gch = klch ^ (row & 7);
                gld16(kg + (size_t)row * DD + gch * 8, &Ks[0][r0 * 128]);
            }
            vr0 = *(const uint4*)(vg + (size_t)(2 * pr) * DD + hc);
            vr1 = *(const uint4*)(vg + (size_t)(2 * pr) * DD + hc + 8);
            vr2 = *(const uint4*)(vg + (size_t)(2 * pr + 1) * DD + hc);
            vr3 = *(const uint4*)(vg + (size_t)(2 * pr + 1) * DD + hc + 8);
        }

        for (int kt = 0; kt < nkt; kt++) {
            const int cur = kt & 1;
            __syncthreads();   // barrier A: drains K/V prefetch; prior tile reads done
            // ---- issue K(kt+1) gld16 into the other K buffer (max cover) ----
            if (kt + 1 < nkt) {
                const unsigned short* kg = k + (rowbase + (kt + 1) * 64) * DD + hcol;
                #pragma unroll
                for (int i = 0; i < 4; i++) {
                    const int r0 = wave * 16 + i * 4;
                    const int row = r0 + klrow;
                    const int gch = klch ^ (row & 7);
                    gld16(kg + (size_t)row * DD + gch * 8, &Ks[cur ^ 1][r0 * 128]);
                }
            }
            // ---- commit V(kt): packed b32 scatter-transpose into Vts ----
            {
                const unsigned short* s0 = (const unsigned short*)&vr0;
                const unsigned short* s1 = (const unsigned short*)&vr1;
                const unsigned short* s2 = (const unsigned short*)&vr2;
                const unsigned short* s3 = (const unsigned short*)&vr3;
                #pragma unroll
                for (int jj = 0; jj < 8; jj++) {
                    *(uint32_t*)(&Vts[(hc + jj) * 64 + vsw0]) =
                        (uint32_t)s0[jj] | ((uint32_t)s2[jj] << 16);
                    *(uint32_t*)(&Vts[(hc + 8 + jj) * 64 + vsw1]) =
                        (uint32_t)s1[jj] | ((uint32_t)s3[jj] << 16);
                }
            }
            // ---- issue V(kt+1) global loads ----
            if (kt + 1 < nkt) {
                const unsigned short* vg = v + (rowbase + (kt + 1) * 64) * DD + hcol;
                vr0 = *(const uint4*)(vg + (size_t)(2 * pr) * DD + hc);
                vr1 = *(const uint4*)(vg + (size_t)(2 * pr) * DD + hc + 8);
                vr2 = *(const uint4*)(vg + (size_t)(2 * pr + 1) * DD + hc);
                vr3 = *(const uint4*)(vg + (size_t)(2 * pr + 1) * DD + hc + 8);
            }
            // ---- S = Q K^T from Ks[cur] (swizzled read) ----
            const unsigned short* ksc = &Ks[cur][0];
            f32x4 accs[4];
            #pragma unroll
            for (int j = 0; j < 4; j++) accs[j] = zf;
            __builtin_amdgcn_s_setprio(1);
            #pragma unroll
            for (int j = 0; j < 4; j++)
                #pragma unroll
                for (int kk = 0; kk < 4; kk++) {
                    bf16x8 bk = *(const bf16x8*)(&ksc[(j * 16 + l15) * 128 +
                                                      (((kk * 4 + lq) ^ (l15 & 7)) * 8)]);
                    accs[j] = MF(aq[kk], bk, accs[j]);
                }
            __builtin_amdgcn_s_setprio(0);
            // scale + causal mask + rowmax
            const int kbase = kt * 64;
            float rowmax[4] = {-1e30f, -1e30f, -1e30f, -1e30f};
            #pragma unroll
            for (int j = 0; j < 4; j++) {
                const int kp = kbase + j * 16 + l15;
                #pragma unroll
                for (int r = 0; r < 4; r++) {
                    float s = accs[j][r] * scale;
                    s = (kp > qp0 + r) ? -1e30f : s;
                    accs[j][r] = s;
                    rowmax[r] = fmaxf(rowmax[r], s);
                }
            }
            #pragma unroll
            for (int r = 0; r < 4; r++) {
                float mx = rowmax[r];
                mx = fmaxf(mx, __shfl_xor(mx, 1, 64));
                mx = fmaxf(mx, __shfl_xor(mx, 2, 64));
                mx = fmaxf(mx, __shfl_xor(mx, 4, 64));
                mx = fmaxf(mx, __shfl_xor(mx, 8, 64));
                float m_new = fmaxf(m_i[r], mx);
                float al = __expf(m_i[r] - m_new);
                m_i[r] = m_new;
                l_i[r] *= al;
                #pragma unroll
                for (int jh = 0; jh < 8; jh++) acc_o[jh][r] *= al;
            }
            // P = exp(S - m) -> wave-private LDS (C-layout -> A-layout)
            float rowsum[4] = {0.f, 0.f, 0.f, 0.f};
            #pragma unroll
            for (int j = 0; j < 4; j++)
                #pragma unroll
                for (int r = 0; r < 4; r++) {
                    float p = __expf(accs[j][r] - m_i[r]);
                    rowsum[r] += p;
                    Pw[(lq * 4 + r) * LPP + j * 16 + l15] = f2bf(p);
                }
            #pragma unroll
            for (int r = 0; r < 4; r++) {
                float s = rowsum[r];
                s += __shfl_xor(s, 1, 64);
                s += __shfl_xor(s, 2, 64);
                s += __shfl_xor(s, 4, 64);
                s += __shfl_xor(s, 8, 64);
                l_i[r] += s;
            }
            __syncthreads();   // barrier B: V(kt) scatter + P visible
            // ---- O += P @ V ----
            bf16x8 ap[2];
            #pragma unroll
            for (int kk = 0; kk < 2; kk++)
                ap[kk] = *(const bf16x8*)(&Pw[l15 * LPP + kk * 32 + lq * 8]);
            __builtin_amdgcn_s_setprio(1);
            #pragma unroll
            for (int jh = 0; jh < 8; jh++) {
                const int hd = jh * 16 + l15;
                const int vswz = ((hd >> 3) & 7) << 3;
                #pragma unroll
                for (int kk = 0; kk < 2; kk++) {
                    bf16x8 bv = *(const bf16x8*)(&Vts[hd * 64 + ((kk * 32 + lq * 8) ^ vswz)]);
                    acc_o[jh] = MF(ap[kk], bv, acc_o[jh]);
                }
            }
            __builtin_amdgcn_s_setprio(0);
        }
        // epilogue: O / l
        #pragma unroll
        for (int jh = 0; jh < 8; jh++) {
            const int col = hcol + jh * 16 + l15;
            #pragma unroll
            for (int r = 0; r < 4; r++)
                o[(rowbase + qp0 + r) * DD + col] = f2bf(acc_o[jh][r] * (1.0f / l_i[r]));
        }
    }
}

extern "C" void kernel_launch(void* const* d_in, const int* in_sizes, int n_in,
                              void* d_out, int out_size, void* d_ws, size_t ws_size,
                              hipStream_t stream) {
    const float* x      = (const float*)d_in[0];
    // d_in[1] = attn_mask: deterministic causal tril -> handled analytically
    const float* w_norm = (const float*)d_in[2];
    const float* wq     = (const float*)d_in[3];
    const float* wk     = (const float*)d_in[4];
    const float* wv     = (const float*)d_in[5];
    const float* wo     = (const float*)d_in[6];

    unsigned short* wbf = (unsigned short*)d_ws;                 // [4][D*D]
    unsigned short* xn  = wbf + (size_t)4 * DD * DD;             // [BT][D]
    unsigned short* qb  = xn + (size_t)BTT * DD;
    unsigned short* kb  = qb + (size_t)BTT * DD;
    unsigned short* vb  = kb + (size_t)BTT * DD;
    unsigned short* ab  = vb + (size_t)BTT * DD;

    convert_w<<<8192, 256, 0, stream>>>(wq, wk, wv, wo, wbf);
    rmsnorm_k<<<BTT, 256, 0, stream>>>(x, w_norm, xn);
    dim3 gqkv(32, 24);
    gemm_qkv<<<gqkv, 512, 0, stream>>>(xn, wbf, qb);
    dim3 gattn(16, NHH, 2);
    attn_fused<<<gattn, 256, 0, stream>>>(qb, kb, vb, ab);
    dim3 gout(32, 8);
    gemm_out<<<gout, 512, 0, stream>>>(ab, wbf + (size_t)3 * DD * DD, (float*)d_out);
}

// Round 7
// 412.386 us; speedup vs baseline: 1.0811x; 1.0349x over previous
//
#include <hip/hip_runtime.h>
#include <stdint.h>

#define TT 2048
#define DD 2048
#define NHH 16
#define HDD 128
#define BTT 4096   // B*T

typedef __attribute__((ext_vector_type(8))) short bf16x8;
typedef __attribute__((ext_vector_type(4))) float f32x4;

#define MF(a, b, c) __builtin_amdgcn_mfma_f32_16x16x32_bf16(a, b, c, 0, 0, 0)

__device__ __forceinline__ unsigned short f2bf(float f) {
    union { float f; uint32_t u; } v; v.f = f;
    uint32_t u = v.u;
    u += 0x7fffu + ((u >> 16) & 1u);   // RNE
    return (unsigned short)(u >> 16);
}

// async global->LDS, 16B per lane. LDS dest = wave-uniform base + lane*16B.
__device__ __forceinline__ void gld16(const unsigned short* g, unsigned short* l) {
    __builtin_amdgcn_global_load_lds(
        (const __attribute__((address_space(1))) unsigned int*)g,
        (__attribute__((address_space(3))) unsigned int*)l, 16, 0, 0);
}

// ---------------- weight fp32 -> bf16 cast ----------------
__global__ __launch_bounds__(256) void convert_w(const float* __restrict__ wq,
                                                 const float* __restrict__ wk,
                                                 const float* __restrict__ wv,
                                                 const float* __restrict__ wo,
                                                 unsigned short* __restrict__ out) {
    size_t gid = (size_t)blockIdx.x * 256 + threadIdx.x;
    size_t base = gid * 8;
    int which = (int)(base >> 22);
    const float* src = which == 0 ? wq : which == 1 ? wk : which == 2 ? wv : wo;
    size_t off = base & 4194303u;
    float4 a = ((const float4*)(src + off))[0];
    float4 b = ((const float4*)(src + off))[1];
    union { unsigned short us[8]; uint4 v; } pk;
    pk.us[0] = f2bf(a.x); pk.us[1] = f2bf(a.y); pk.us[2] = f2bf(a.z); pk.us[3] = f2bf(a.w);
    pk.us[4] = f2bf(b.x); pk.us[5] = f2bf(b.y); pk.us[6] = f2bf(b.z); pk.us[7] = f2bf(b.w);
    *(uint4*)(out + base) = pk.v;
}

// ---------------- RMSNorm fp32 -> bf16 ----------------
__global__ __launch_bounds__(256) void rmsnorm_k(const float* __restrict__ x,
                                                 const float* __restrict__ w,
                                                 unsigned short* __restrict__ xn) {
    const int row = blockIdx.x;
    const int tid = threadIdx.x;
    const float* xr = x + (size_t)row * DD;
    float4 a = ((const float4*)xr)[tid * 2];
    float4 b = ((const float4*)xr)[tid * 2 + 1];
    float ss = a.x*a.x + a.y*a.y + a.z*a.z + a.w*a.w
             + b.x*b.x + b.y*b.y + b.z*b.z + b.w*b.w;
    #pragma unroll
    for (int m = 1; m < 64; m <<= 1) ss += __shfl_xor(ss, m, 64);
    __shared__ float wss[4];
    if ((tid & 63) == 0) wss[tid >> 6] = ss;
    __syncthreads();
    float total = wss[0] + wss[1] + wss[2] + wss[3];
    float norm = sqrtf(total) * 0.022097086912079612f;
    float inv = 1.0f / (norm + 1e-8f);
    float4 wa = ((const float4*)w)[tid * 2];
    float4 wb = ((const float4*)w)[tid * 2 + 1];
    union { unsigned short us[8]; uint4 v; } pk;
    pk.us[0] = f2bf(wa.x * a.x * inv); pk.us[1] = f2bf(wa.y * a.y * inv);
    pk.us[2] = f2bf(wa.z * a.z * inv); pk.us[3] = f2bf(wa.w * a.w * inv);
    pk.us[4] = f2bf(wb.x * b.x * inv); pk.us[5] = f2bf(wb.y * b.y * inv);
    pk.us[6] = f2bf(wb.z * b.z * inv); pk.us[7] = f2bf(wb.w * b.w * inv);
    ((uint4*)(xn + (size_t)row * DD))[tid] = pk.v;
}

// ---------------- 128x256 triple-buffer counted-vmcnt GEMM core (R7) ----------------
// 512 thr = 8 waves (2M x 4N), per-wave 64x64 out, BK=64.
// LDS 144 KiB: 3 bufs x (A 128x64 + B 256x64), 2B elems. Staging/swizzle identical to R5
// (correctness-proven). NEW: T4 counted vmcnt -- stage tile kt+2 during kt; end-of-tile
// wait = vmcnt(6): tile kt+1's 6 loads (oldest, in-order FIFO) complete; kt+2's 6 stay in
// flight. Every load gets ~2 k-tiles (~1400cy) of cover >= 900cy HBM latency. Never
// drains to 0 in steady state (R4/R5's failure mode). One s_barrier per k-tile.
// Safety: each wave vmcnt-waits its OWN loads before the barrier; barrier publishes all;
// stage target buf (kt+2 == kt-1 mod 3) was last read before the previous barrier.
__device__ __forceinline__ void stage_tile(const unsigned short* __restrict__ Ag,
                                           const unsigned short* __restrict__ Bg,
                                           int k0, unsigned short* buf,
                                           int swA, int swB, size_t goff) {
    #pragma unroll
    for (int c = 0; c < 2; c++)
        gld16(Ag + (size_t)(swA + c * 8) * DD + k0 + goff, buf + (swA + c * 8) * 64);
    #pragma unroll
    for (int c = 0; c < 4; c++)
        gld16(Bg + (size_t)(swB + c * 8) * DD + k0 + goff, buf + 8192 + (swB + c * 8) * 64);
}

__device__ __forceinline__ void gemm128x256_core(const unsigned short* __restrict__ Ag,
                                                 const unsigned short* __restrict__ Bg,
                                                 unsigned short* lds, f32x4 acc[4][4]) {
    const int tid = threadIdx.x;
    const int wave = tid >> 6, lane = tid & 63;
    const int wm = wave >> 2, wn = wave & 3;
    const int l15 = lane & 15, lq = lane >> 4, r7 = l15 & 7;
    const int gr = lane >> 3;
    const size_t goff = (size_t)gr * DD + (size_t)(((lane & 7) ^ gr) * 8);
    const int xk0 = (lq ^ r7) * 8;         // k-half 0 chunk (de-swizzled)
    const int xk1 = ((4 + lq) ^ r7) * 8;   // k-half 1 chunk
    const int aro = (wm * 64 + l15) * 64;
    const int bro = 8192 + (wn * 64 + l15) * 64;
    const int swA = wave * 16;   // wave's A staging rows (2 chunks of 8)
    const int swB = wave * 32;   // wave's B staging rows (4 chunks of 8)
    unsigned short* p0 = lds;            // compute buffer (tile kt)
    unsigned short* p1 = lds + 24576;    // tile kt+1 (in flight / landed)
    unsigned short* p2 = lds + 49152;    // tile kt+2 (stage target)

    // ---- prologue: stage tiles 0 and 1; wait tile 0 (vmcnt(6): tile1 stays in flight) ----
    stage_tile(Ag, Bg, 0, p0, swA, swB, goff);
    stage_tile(Ag, Bg, 64, p1, swA, swB, goff);
    asm volatile("s_waitcnt vmcnt(6)" ::: "memory");
    __builtin_amdgcn_sched_barrier(0);
    __builtin_amdgcn_s_barrier();

    for (int kt = 0; kt < 32; kt++) {
        if (kt + 2 < 32)
            stage_tile(Ag, Bg, (kt + 2) * 64, p2, swA, swB, goff);
        const unsigned short* ac = p0 + aro;
        const unsigned short* bc = p0 + bro;
        bf16x8 a[4][2], b[4][2];
        #pragma unroll
        for (int m = 0; m < 4; m++) {
            a[m][0] = *(const bf16x8*)(ac + m * 1024 + xk0);
            a[m][1] = *(const bf16x8*)(ac + m * 1024 + xk1);
        }
        #pragma unroll
        for (int n = 0; n < 4; n++) {
            b[n][0] = *(const bf16x8*)(bc + n * 1024 + xk0);
            b[n][1] = *(const bf16x8*)(bc + n * 1024 + xk1);
        }
        asm volatile("s_waitcnt lgkmcnt(0)" ::: "memory");
        __builtin_amdgcn_sched_barrier(0);
        __builtin_amdgcn_s_setprio(1);
        #pragma unroll
        for (int m = 0; m < 4; m++)
            #pragma unroll
            for (int n = 0; n < 4; n++) {
                acc[m][n] = MF(a[m][0], b[n][0], acc[m][n]);
                acc[m][n] = MF(a[m][1], b[n][1], acc[m][n]);
            }
        __builtin_amdgcn_s_setprio(0);
        if (kt + 1 < 32) {
            if (kt + 2 < 32) { asm volatile("s_waitcnt vmcnt(6)" ::: "memory"); }
            else             { asm volatile("s_waitcnt vmcnt(0)" ::: "memory"); }
            __builtin_amdgcn_sched_barrier(0);
        }
        __builtin_amdgcn_s_barrier();
        unsigned short* t = p0; p0 = p1; p1 = p2; p2 = t;
    }
}

// fused QKV: 768 blocks (32x8x3) x 512 thr = 3 exact full GPU rounds
__global__ __launch_bounds__(512, 2) void gemm_qkv(const unsigned short* __restrict__ A,
                                                   const unsigned short* __restrict__ W3,
                                                   unsigned short* __restrict__ O3) {
    __shared__ __align__(16) unsigned short lds[73728];   // 144 KiB, 3 bufs
    const int orig = blockIdx.y * 32 + blockIdx.x;        // grid (32, 24)
    const int id = (orig & 7) * 96 + (orig >> 3);         // bijective XCD swizzle (768%8==0)
    const int which = id >> 8;
    const int rem = id & 255;
    const int bn = rem >> 5, bm = rem & 31;               // consecutive ids share B panel
    const unsigned short* Bw = W3 + (size_t)which * DD * DD;
    unsigned short* C = O3 + (size_t)which * BTT * DD;
    const int m0 = bm * 128, n0 = bn * 256;
    const f32x4 zf = {0.f, 0.f, 0.f, 0.f};
    f32x4 acc[4][4];
    #pragma unroll
    for (int m = 0; m < 4; m++)
        #pragma unroll
        for (int n = 0; n < 4; n++) acc[m][n] = zf;
    gemm128x256_core(A + (size_t)m0 * DD, Bw + (size_t)n0 * DD, lds, acc);
    const int wave = threadIdx.x >> 6, lane = threadIdx.x & 63;
    const int wm = wave >> 2, wn = wave & 3;
    const int l15 = lane & 15, lq = lane >> 4;
    #pragma unroll
    for (int m = 0; m < 4; m++) {
        const int row = m0 + wm * 64 + m * 16 + lq * 4;
        #pragma unroll
        for (int n = 0; n < 4; n++) {
            const int col = n0 + wn * 64 + n * 16 + l15;
            #pragma unroll
            for (int r = 0; r < 4; r++)
                C[(size_t)(row + r) * DD + col] = f2bf(acc[m][n][r]);
        }
    }
}

// final proj, fp32 out: 256 blocks (32x8) x 512 thr = 1 exact full GPU round
__global__ __launch_bounds__(512, 2) void gemm_out(const unsigned short* __restrict__ A,
                                                   const unsigned short* __restrict__ Bw,
                                                   float* __restrict__ C) {
    __shared__ __align__(16) unsigned short lds[73728];   // 144 KiB, 3 bufs
    const int orig = blockIdx.y * 32 + blockIdx.x;        // grid (32, 8)
    const int id = (orig & 7) * 32 + (orig >> 3);         // bijective XCD swizzle (256%8==0)
    const int bn = id >> 5, bm = id & 31;
    const int m0 = bm * 128, n0 = bn * 256;
    const f32x4 zf = {0.f, 0.f, 0.f, 0.f};
    f32x4 acc[4][4];
    #pragma unroll
    for (int m = 0; m < 4; m++)
        #pragma unroll
        for (int n = 0; n < 4; n++) acc[m][n] = zf;
    gemm128x256_core(A + (size_t)m0 * DD, Bw + (size_t)n0 * DD, lds, acc);
    const int wave = threadIdx.x >> 6, lane = threadIdx.x & 63;
    const int wm = wave >> 2, wn = wave & 3;
    const int l15 = lane & 15, lq = lane >> 4;
    #pragma unroll
    for (int m = 0; m < 4; m++) {
        const int row = m0 + wm * 64 + m * 16 + lq * 4;
        #pragma unroll
        for (int n = 0; n < 4; n++) {
            const int col = n0 + wn * 64 + n * 16 + l15;
            #pragma unroll
            for (int r = 0; r < 4; r++)
                C[(size_t)(row + r) * DD + col] = acc[m][n][r];
        }
    }
}

// ---------------- fused causal flash attention, paired q-tiles (R6, unchanged) ----------------
__global__ __launch_bounds__(256) void attn_fused(const unsigned short* __restrict__ q,
                                                  const unsigned short* __restrict__ k,
                                                  const unsigned short* __restrict__ v,
                                                  unsigned short* __restrict__ o) {
    constexpr int LPP = 72;   // 64 + 8 pad
    __shared__ __align__(16) unsigned short Ks[2][64 * 128];
    __shared__ __align__(16) unsigned short Vts[128 * 64];
    __shared__ __align__(16) unsigned short Ps[4 * 16 * LPP];
    const int h = blockIdx.y, b = blockIdx.z;
    const int tid = threadIdx.x, wave = tid >> 6, lane = tid & 63;
    const int l15 = lane & 15, lq = lane >> 4;
    const size_t rowbase = (size_t)b * TT;
    const int hcol = h * HDD;
    const float scale = 0.08838834764831845f;  // HD^-0.5
    unsigned short* Pw = Ps + wave * 16 * LPP;
    const f32x4 zf = {0.f, 0.f, 0.f, 0.f};

    uint4 vr0, vr1, vr2, vr3;
    const int pr = tid >> 3;            // 0..31
    const int hc = (tid & 7) * 16;      // 0,16,...,112
    const int vsw0 = (2 * pr) ^ (((hc >> 3) & 7) << 3);
    const int vsw1 = (2 * pr) ^ ((((hc + 8) >> 3) & 7) << 3);

    const int klrow = lane >> 4;        // 0..3
    const int klch  = lane & 15;

    for (int half = 0; half < 2; half++) {
        const int qj = (half == 0) ? blockIdx.x : 31 - blockIdx.x;
        const int qt0 = qj * 64;
        bf16x8 aq[4];
        {
            const unsigned short* qrp = q + (rowbase + qt0 + wave * 16 + l15) * DD + hcol;
            #pragma unroll
            for (int kk = 0; kk < 4; kk++)
                aq[kk] = *(const bf16x8*)(qrp + kk * 32 + lq * 8);
        }
        f32x4 acc_o[8];
        #pragma unroll
        for (int jh = 0; jh < 8; jh++) acc_o[jh] = zf;
        float m_i[4], l_i[4];
        #pragma unroll
        for (int r = 0; r < 4; r++) { m_i[r] = -1e30f; l_i[r] = 0.f; }
        const int qp0 = qt0 + wave * 16 + lq * 4;
        const int nkt = qj + 1;

        __syncthreads();
        {
            const unsigned short* kg = k + rowbase * DD + hcol;
            const unsigned short* vg = v + rowbase * DD + hcol;
            #pragma unroll
            for (int i = 0; i < 4; i++) {
                const int r0 = wave * 16 + i * 4;
                const int row = r0 + klrow;
                const int gch = klch ^ (row & 7);
                gld16(kg + (size_t)row * DD + gch * 8, &Ks[0][r0 * 128]);
            }
            vr0 = *(const uint4*)(vg + (size_t)(2 * pr) * DD + hc);
            vr1 = *(const uint4*)(vg + (size_t)(2 * pr) * DD + hc + 8);
            vr2 = *(const uint4*)(vg + (size_t)(2 * pr + 1) * DD + hc);
            vr3 = *(const uint4*)(vg + (size_t)(2 * pr + 1) * DD + hc + 8);
        }

        for (int kt = 0; kt < nkt; kt++) {
            const int cur = kt & 1;
            __syncthreads();   // barrier A: drains K/V prefetch; prior tile reads done
            if (kt + 1 < nkt) {
                const unsigned short* kg = k + (rowbase + (kt + 1) * 64) * DD + hcol;
                #pragma unroll
                for (int i = 0; i < 4; i++) {
                    const int r0 = wave * 16 + i * 4;
                    const int row = r0 + klrow;
                    const int gch = klch ^ (row & 7);
                    gld16(kg + (size_t)row * DD + gch * 8, &Ks[cur ^ 1][r0 * 128]);
                }
            }
            {
                const unsigned short* s0 = (const unsigned short*)&vr0;
                const unsigned short* s1 = (const unsigned short*)&vr1;
                const unsigned short* s2 = (const unsigned short*)&vr2;
                const unsigned short* s3 = (const unsigned short*)&vr3;
                #pragma unroll
                for (int jj = 0; jj < 8; jj++) {
                    *(uint32_t*)(&Vts[(hc + jj) * 64 + vsw0]) =
                        (uint32_t)s0[jj] | ((uint32_t)s2[jj] << 16);
                    *(uint32_t*)(&Vts[(hc + 8 + jj) * 64 + vsw1]) =
                        (uint32_t)s1[jj] | ((uint32_t)s3[jj] << 16);
                }
            }
            if (kt + 1 < nkt) {
                const unsigned short* vg = v + (rowbase + (kt + 1) * 64) * DD + hcol;
                vr0 = *(const uint4*)(vg + (size_t)(2 * pr) * DD + hc);
                vr1 = *(const uint4*)(vg + (size_t)(2 * pr) * DD + hc + 8);
                vr2 = *(const uint4*)(vg + (size_t)(2 * pr + 1) * DD + hc);
                vr3 = *(const uint4*)(vg + (size_t)(2 * pr + 1) * DD + hc + 8);
            }
            const unsigned short* ksc = &Ks[cur][0];
            f32x4 accs[4];
            #pragma unroll
            for (int j = 0; j < 4; j++) accs[j] = zf;
            __builtin_amdgcn_s_setprio(1);
            #pragma unroll
            for (int j = 0; j < 4; j++)
                #pragma unroll
                for (int kk = 0; kk < 4; kk++) {
                    bf16x8 bk = *(const bf16x8*)(&ksc[(j * 16 + l15) * 128 +
                                                      (((kk * 4 + lq) ^ (l15 & 7)) * 8)]);
                    accs[j] = MF(aq[kk], bk, accs[j]);
                }
            __builtin_amdgcn_s_setprio(0);
            const int kbase = kt * 64;
            float rowmax[4] = {-1e30f, -1e30f, -1e30f, -1e30f};
            #pragma unroll
            for (int j = 0; j < 4; j++) {
                const int kp = kbase + j * 16 + l15;
                #pragma unroll
                for (int r = 0; r < 4; r++) {
                    float s = accs[j][r] * scale;
                    s = (kp > qp0 + r) ? -1e30f : s;
                    accs[j][r] = s;
                    rowmax[r] = fmaxf(rowmax[r], s);
                }
            }
            #pragma unroll
            for (int r = 0; r < 4; r++) {
                float mx = rowmax[r];
                mx = fmaxf(mx, __shfl_xor(mx, 1, 64));
                mx = fmaxf(mx, __shfl_xor(mx, 2, 64));
                mx = fmaxf(mx, __shfl_xor(mx, 4, 64));
                mx = fmaxf(mx, __shfl_xor(mx, 8, 64));
                float m_new = fmaxf(m_i[r], mx);
                float al = __expf(m_i[r] - m_new);
                m_i[r] = m_new;
                l_i[r] *= al;
                #pragma unroll
                for (int jh = 0; jh < 8; jh++) acc_o[jh][r] *= al;
            }
            float rowsum[4] = {0.f, 0.f, 0.f, 0.f};
            #pragma unroll
            for (int j = 0; j < 4; j++)
                #pragma unroll
                for (int r = 0; r < 4; r++) {
                    float p = __expf(accs[j][r] - m_i[r]);
                    rowsum[r] += p;
                    Pw[(lq * 4 + r) * LPP + j * 16 + l15] = f2bf(p);
                }
            #pragma unroll
            for (int r = 0; r < 4; r++) {
                float s = rowsum[r];
                s += __shfl_xor(s, 1, 64);
                s += __shfl_xor(s, 2, 64);
                s += __shfl_xor(s, 4, 64);
                s += __shfl_xor(s, 8, 64);
                l_i[r] += s;
            }
            __syncthreads();   // barrier B: V(kt) scatter + P visible
            bf16x8 ap[2];
            #pragma unroll
            for (int kk = 0; kk < 2; kk++)
                ap[kk] = *(const bf16x8*)(&Pw[l15 * LPP + kk * 32 + lq * 8]);
            __builtin_amdgcn_s_setprio(1);
            #pragma unroll
            for (int jh = 0; jh < 8; jh++) {
                const int hd = jh * 16 + l15;
                const int vswz = ((hd >> 3) & 7) << 3;
                #pragma unroll
                for (int kk = 0; kk < 2; kk++) {
                    bf16x8 bv = *(const bf16x8*)(&Vts[hd * 64 + ((kk * 32 + lq * 8) ^ vswz)]);
                    acc_o[jh] = MF(ap[kk], bv, acc_o[jh]);
                }
            }
            __builtin_amdgcn_s_setprio(0);
        }
        #pragma unroll
        for (int jh = 0; jh < 8; jh++) {
            const int col = hcol + jh * 16 + l15;
            #pragma unroll
            for (int r = 0; r < 4; r++)
                o[(rowbase + qp0 + r) * DD + col] = f2bf(acc_o[jh][r] * (1.0f / l_i[r]));
        }
    }
}

extern "C" void kernel_launch(void* const* d_in, const int* in_sizes, int n_in,
                              void* d_out, int out_size, void* d_ws, size_t ws_size,
                              hipStream_t stream) {
    const float* x      = (const float*)d_in[0];
    // d_in[1] = attn_mask: deterministic causal tril -> handled analytically
    const float* w_norm = (const float*)d_in[2];
    const float* wq     = (const float*)d_in[3];
    const float* wk     = (const float*)d_in[4];
    const float* wv     = (const float*)d_in[5];
    const float* wo     = (const float*)d_in[6];

    unsigned short* wbf = (unsigned short*)d_ws;                 // [4][D*D]
    unsigned short* xn  = wbf + (size_t)4 * DD * DD;             // [BT][D]
    unsigned short* qb  = xn + (size_t)BTT * DD;
    unsigned short* kb  = qb + (size_t)BTT * DD;
    unsigned short* vb  = kb + (size_t)BTT * DD;
    unsigned short* ab  = vb + (size_t)BTT * DD;

    convert_w<<<8192, 256, 0, stream>>>(wq, wk, wv, wo, wbf);
    rmsnorm_k<<<BTT, 256, 0, stream>>>(x, w_norm, xn);
    dim3 gqkv(32, 24);
    gemm_qkv<<<gqkv, 512, 0, stream>>>(xn, wbf, qb);
    dim3 gattn(16, NHH, 2);
    attn_fused<<<gattn, 256, 0, stream>>>(qb, kb, vb, ab);
    dim3 gout(32, 8);
    gemm_out<<<gout, 512, 0, stream>>>(ab, wbf + (size_t)3 * DD * DD, (float*)d_out);
}